// Round 2
// baseline (5174.520 us; speedup 1.0000x reference)
//
#include <hip/hip_runtime.h>

#define Bb 8
#define Cc 128
#define Hh 128
#define Ww 128
#define HW 16384
#define CHW (Cc*HW)
#define NHW (Bb*HW)
#define CH 16
#define EPS 1e-5f

// ---------------- LayerNorm over channel dim ----------------
__global__ __launch_bounds__(256) void k_ln(const float* __restrict__ x,
    const float* __restrict__ g, const float* __restrict__ be,
    float* __restrict__ y)
{
  int p = blockIdx.x*256 + threadIdx.x;     // 0..131071  (b,hw)
  int b = p >> 14, hw = p & 16383;
  const float* xp = x + (long)b*CHW + hw;
  float s = 0.f, q = 0.f;
  for (int c = 0; c < Cc; ++c) { float v = xp[c*HW]; s += v; q += v*v; }
  float mu = s * (1.f/Cc);
  float var = q * (1.f/Cc) - mu*mu;
  float rstd = rsqrtf(var + EPS);
  float* yp = y + (long)b*CHW + hw;
  for (int c = 0; c < Cc; ++c) {
    float v = xp[c*HW];
    yp[c*HW] = (v - mu) * rstd * g[c] + be[c];
  }
}

// ---------------- 3x3 weight reorg: [co][ci][tap] -> [tap][ci*128+co] ----------------
__global__ __launch_bounds__(256) void k_reorg(const float* __restrict__ Wt, float* __restrict__ out)
{
  int idx = blockIdx.x*256 + threadIdx.x;   // < 147456
  int tap = idx >> 14, r = idx & 16383;
  int ci = r >> 7, co = r & 127;
  out[idx] = Wt[(co*128 + ci)*9 + tap];
}

// ---------------- 1x1 weight reorg: [co][ci] -> [ci*128+co] ----------------
__global__ __launch_bounds__(256) void k_reorg1(const float* __restrict__ Wt, float* __restrict__ out)
{
  int idx = blockIdx.x*256 + threadIdx.x;   // < 16384
  int ci = idx >> 7, co = idx & 127;
  out[idx] = Wt[co*128 + ci];
}

__global__ __launch_bounds__(256) void k_zero(float* p, int n)
{
  int i = blockIdx.x*256 + threadIdx.x;
  if (i < n) p[i] = 0.f;
}

// ---------------- dense conv (1x1 or 3x3 dilated). W pre-laid [tap][ci][co] ----------------
// block: 128 co x 128 w (one row h); thread: 8 co x 8 w. LDS: 8KB W-chunk + 8KB X-row.
__global__ __launch_bounds__(256,2) void k_conv(const float* __restrict__ X,
    const float* __restrict__ Wt, const float* __restrict__ res,
    float* __restrict__ Y, int k3, int dil)
{
  __shared__ float Wc[2048];    // [k16][co128]
  __shared__ float Xs[2048];    // [k16][w128]
  int bid = blockIdx.x;
  int b = bid >> 7, h = bid & 127;
  int t = threadIdx.x;
  int co0 = (t & 15) << 3;
  int sp0 = (t >> 4) << 3;
  float acc[8][8];
  #pragma unroll
  for (int i = 0; i < 8; ++i)
    #pragma unroll
    for (int j = 0; j < 8; ++j) acc[i][j] = 0.f;
  int half = k3 >> 1;
  for (int kh = 0; kh < k3; ++kh) {
    int hs = h + (kh - half)*dil;
    if ((unsigned)hs >= (unsigned)Hh) continue;       // block-uniform
    for (int kw = 0; kw < k3; ++kw) {
      int dw = (kw - half)*dil;
      const float* wbase = Wt + (kh*k3 + kw)*16384;
      for (int kc = 0; kc < 8; ++kc) {
        __syncthreads();
        { const float4* wsrc = (const float4*)(wbase + kc*2048);
          ((float4*)Wc)[t]       = wsrc[t];
          ((float4*)Wc)[t + 256] = wsrc[t + 256]; }
        { int cl = t >> 4, wb = (t & 15) << 3;
          const float* sx = X + ((long)(b*Cc + kc*16 + cl)*Hh + hs)*Ww + dw;
          #pragma unroll
          for (int i = 0; i < 8; ++i) {
            int wsrc = wb + i + dw;
            Xs[cl*128 + wb + i] = ((unsigned)wsrc < (unsigned)Ww) ? sx[wb + i] : 0.f;
          }
        }
        __syncthreads();
        #pragma unroll
        for (int k = 0; k < 16; ++k) {
          float4 wa = *(const float4*)&Wc[k*128 + co0];
          float4 wb4 = *(const float4*)&Wc[k*128 + co0 + 4];
          float4 xa = *(const float4*)&Xs[k*128 + sp0];
          float4 xb = *(const float4*)&Xs[k*128 + sp0 + 4];
          float wv[8] = {wa.x,wa.y,wa.z,wa.w,wb4.x,wb4.y,wb4.z,wb4.w};
          float xv[8] = {xa.x,xa.y,xa.z,xa.w,xb.x,xb.y,xb.z,xb.w};
          #pragma unroll
          for (int i = 0; i < 8; ++i)
            #pragma unroll
            for (int j = 0; j < 8; ++j)
              acc[i][j] = fmaf(wv[i], xv[j], acc[i][j]);
        }
      }
    }
  }
  #pragma unroll
  for (int i = 0; i < 8; ++i) {
    long idx = ((long)(b*Cc + co0 + i)*Hh + h)*Ww + sp0;
    float4 r0, r1;
    r0.x=acc[i][0]; r0.y=acc[i][1]; r0.z=acc[i][2]; r0.w=acc[i][3];
    r1.x=acc[i][4]; r1.y=acc[i][5]; r1.z=acc[i][6]; r1.w=acc[i][7];
    if (res) {
      float4 a = *(const float4*)&res[idx];
      float4 bv = *(const float4*)&res[idx+4];
      r0.x+=a.x; r0.y+=a.y; r0.z+=a.z; r0.w+=a.w;
      r1.x+=bv.x; r1.y+=bv.y; r1.z+=bv.z; r1.w+=bv.w;
    }
    *(float4*)&Y[idx] = r0;
    *(float4*)&Y[idx+4] = r1;
  }
}

// ---------------- BN batch stats (sum, sumsq per channel, 3 tensors) ----------------
__global__ __launch_bounds__(256) void k_bnstats(const float* __restrict__ y1,
    const float* __restrict__ y2, const float* __restrict__ y3,
    float* __restrict__ stats)
{
  __shared__ float red[512];
  int bid = blockIdx.x;                 // 3*128*8
  int tsel = bid >> 10;
  int rem = bid & 1023;
  int c = rem >> 3, b = rem & 7;
  const float* y = tsel == 0 ? y1 : (tsel == 1 ? y2 : y3);
  const float* p = y + (long)(b*Cc + c)*HW;
  float s = 0.f, q = 0.f;
  for (int i = threadIdx.x; i < HW; i += 256) { float v = p[i]; s += v; q += v*v; }
  red[threadIdx.x] = s; red[256+threadIdx.x] = q;
  __syncthreads();
  for (int st = 128; st > 0; st >>= 1) {
    if (threadIdx.x < st) {
      red[threadIdx.x] += red[threadIdx.x+st];
      red[256+threadIdx.x] += red[256+threadIdx.x+st];
    }
    __syncthreads();
  }
  if (threadIdx.x == 0) {
    atomicAdd(&stats[tsel*256 + c], red[0]);
    atomicAdd(&stats[tsel*256 + 128 + c], red[256]);
  }
}

// ---------------- BN apply + relu, sum three branches ----------------
__global__ __launch_bounds__(256) void k_bnapply(const float* y1,
    const float* __restrict__ y2, const float* __restrict__ y3,
    const float* __restrict__ stats,
    const float* __restrict__ g1, const float* __restrict__ be1,
    const float* __restrict__ g2, const float* __restrict__ be2,
    const float* __restrict__ g3, const float* __restrict__ be3,
    float* out)
{
  int i4 = blockIdx.x*256 + threadIdx.x;   // float4 index
  int c = (i4 >> 12) & 127;
  const float inv = 1.f/(float)NHW;
  float mu1 = stats[c]*inv;       float v1 = stats[128+c]*inv - mu1*mu1;
  float mu2 = stats[256+c]*inv;   float v2 = stats[384+c]*inv - mu2*mu2;
  float mu3 = stats[512+c]*inv;   float v3 = stats[640+c]*inv - mu3*mu3;
  float s1 = rsqrtf(v1+EPS)*g1[c], s2 = rsqrtf(v2+EPS)*g2[c], s3 = rsqrtf(v3+EPS)*g3[c];
  float o1 = be1[c]-mu1*s1, o2 = be2[c]-mu2*s2, o3_ = be3[c]-mu3*s3;
  float4 a = ((const float4*)y1)[i4];
  float4 bq = ((const float4*)y2)[i4];
  float4 cq = ((const float4*)y3)[i4];
  float4 r;
  r.x = fmaxf(fmaf(a.x,s1,o1),0.f)+fmaxf(fmaf(bq.x,s2,o2),0.f)+fmaxf(fmaf(cq.x,s3,o3_),0.f);
  r.y = fmaxf(fmaf(a.y,s1,o1),0.f)+fmaxf(fmaf(bq.y,s2,o2),0.f)+fmaxf(fmaf(cq.y,s3,o3_),0.f);
  r.z = fmaxf(fmaf(a.z,s1,o1),0.f)+fmaxf(fmaf(bq.z,s2,o2),0.f)+fmaxf(fmaf(cq.z,s3,o3_),0.f);
  r.w = fmaxf(fmaf(a.w,s1,o1),0.f)+fmaxf(fmaf(bq.w,s2,o2),0.f)+fmaxf(fmaf(cq.w,s3,o3_),0.f);
  ((float4*)out)[i4] = r;
}

// ---------------- six depthwise branches summed (with biases) ----------------
__global__ __launch_bounds__(256) void k_dw(const float* __restrict__ X,
    const float* __restrict__ w1, const float* __restrict__ b1,
    const float* __restrict__ w2, const float* __restrict__ b2,
    const float* __restrict__ w3, const float* __restrict__ b3,
    const float* __restrict__ w4, const float* __restrict__ b4,
    const float* __restrict__ w5, const float* __restrict__ b5,
    const float* __restrict__ w6, const float* __restrict__ b6,
    float* __restrict__ Y)
{
  int lin = blockIdx.x*256 + threadIdx.x;
  int w = lin & 127, h = (lin>>7)&127, c = (lin>>14)&127;
  float hcoef[7], vcoef[7];
  #pragma unroll
  for (int d = 0; d < 7; ++d) { hcoef[d] = w5[c*7+d]; vcoef[d] = w6[c*7+d]; }
  #pragma unroll
  for (int d = 1; d < 6; ++d) { hcoef[d] += w1[c*5+d-1]; vcoef[d] += w2[c*5+d-1]; }
  hcoef[3] += w3[c];
  float acc = b1[c]+b2[c]+b3[c]+b4[c]+b5[c]+b6[c];
  const float* xp = X + ((long)lin >> 14 << 14);   // base of (b,c) slab
  #pragma unroll
  for (int d = 0; d < 7; ++d) {
    int wq = w + d - 3;
    if ((unsigned)wq < 128u) acc = fmaf(hcoef[d], xp[h*128 + wq], acc);
    int hq = h + d - 3;
    if ((unsigned)hq < 128u) acc = fmaf(vcoef[d], xp[hq*128 + w], acc);
  }
  #pragma unroll
  for (int kh = 0; kh < 3; ++kh) {
    int hq = h + kh - 1;
    if ((unsigned)hq >= 128u) continue;
    #pragma unroll
    for (int kw = 0; kw < 3; ++kw) {
      int wq = w + kw - 1;
      if ((unsigned)wq < 128u) acc = fmaf(w4[c*9+kh*3+kw], xp[hq*128+wq], acc);
    }
  }
  Y[lin] = acc;
}

// ---------------- norms ----------------
__global__ __launch_bounds__(256) void k_normh(const float* __restrict__ out1, float* __restrict__ invn)
{
  __shared__ float red[256];
  int bid = blockIdx.x;                // (b*8+hd)*128 + h
  int h = bid & 127; int bh = bid >> 7;
  int b = bh >> 3, hd = bh & 7;
  const float* p = out1 + ((long)(b*Cc + hd*CH)*Hh + h)*Ww;
  float s = 0.f;
  for (int e = threadIdx.x; e < 2048; e += 256) {
    int c = e >> 7, w = e & 127;
    float v = p[(long)c*HW + w];
    s += v*v;
  }
  red[threadIdx.x] = s; __syncthreads();
  for (int st = 128; st > 0; st >>= 1) {
    if (threadIdx.x < st) red[threadIdx.x] += red[threadIdx.x+st];
    __syncthreads();
  }
  if (threadIdx.x == 0) invn[bid] = 1.f/fmaxf(sqrtf(red[0]), 1e-12f);
}

__global__ __launch_bounds__(256) void k_normw(const float* __restrict__ out1,
    const float* __restrict__ out2, float* __restrict__ invn1w, float* __restrict__ invn2w)
{
  __shared__ float red[256];
  int bid = blockIdx.x;
  int tsel = bid & 1; int bh = bid >> 1; int b = bh >> 3, hd = bh & 7;
  const float* src = tsel ? out2 : out1;
  int t = threadIdx.x;
  int w = t & 127, half = t >> 7;
  const float* p = src + (long)(b*Cc + hd*CH)*HW + w;
  float s = 0.f;
  for (int c = 0; c < CH; ++c)
    for (int h = half; h < 128; h += 2) {
      float v = p[(long)c*HW + h*128];
      s += v*v;
    }
  red[t] = s; __syncthreads();
  if (t < 128) {
    float tot = red[t] + red[t+128];
    float iv = 1.f/fmaxf(sqrtf(tot), 1e-12f);
    (tsel ? invn2w : invn1w)[bh*128 + w] = iv;
  }
}

// ---------------- S = scaled cross-products + softmax -> A1/A2 ----------------
// grid: type(2) x b(8) x hd(8) x wtile(2); block computes S[64w x 128n], K=2048
__global__ __launch_bounds__(256,2) void k_attnS(const float* __restrict__ out1,
    const float* __restrict__ out2, const float* __restrict__ invn1h,
    const float* __restrict__ invn1w, const float* __restrict__ invn2w,
    float* __restrict__ A1, float* __restrict__ A2)
{
  __shared__ float As[64*16];
  __shared__ float Bs[16][128];
  __shared__ float Smat[64*132];
  int bid = blockIdx.x;
  int wt = bid & 1, hd = (bid>>1)&7, b = (bid>>4)&7, type = bid>>7;
  int w0 = wt*64;
  int t = threadIdx.x;
  int n = t & 127, wl2 = t >> 7;
  const float* srcA = type ? out1 : out2;
  const float* srcB = type ? out2 : out1;
  long slab = (long)(b*Cc + hd*CH)*HW;
  float acc[32];
  #pragma unroll
  for (int j = 0; j < 32; ++j) acc[j] = 0.f;
  for (int kc = 0; kc < 128; ++kc) {
    int cci = kc >> 3;
    int in0 = (kc & 7) << 4;
    const float* pa = srcA + slab + (long)cci*HW;
    const float* pb = srcB + slab + (long)cci*HW;
    __syncthreads();
    for (int e = t; e < 1024; e += 256) {       // As[wl][kl]
      int kl = e >> 6, wl = e & 63;
      As[wl*16 + kl] = pa[(in0+kl)*128 + w0 + wl];
    }
    if (type) {                                  // Bs[kl][n'] = pb[(in0+kl)*128+n']
      for (int e = t; e < 512; e += 256) {
        int kl = e >> 5, q = e & 31;
        *(float4*)&Bs[kl][q*4] = *(const float4*)&pb[(in0+kl)*128 + q*4];
      }
    } else {                                     // Bs[kl][n'] = pb[n'*128+in0+kl] (transpose)
      int nn = t >> 1, pq = t & 1;
      float4 v0 = *(const float4*)&pb[nn*128 + in0 + pq*4];
      float4 v1 = *(const float4*)&pb[nn*128 + in0 + 8 + pq*4];
      Bs[pq*4+0][nn] = v0.x; Bs[pq*4+1][nn] = v0.y;
      Bs[pq*4+2][nn] = v0.z; Bs[pq*4+3][nn] = v0.w;
      Bs[8+pq*4+0][nn] = v1.x; Bs[8+pq*4+1][nn] = v1.y;
      Bs[8+pq*4+2][nn] = v1.z; Bs[8+pq*4+3][nn] = v1.w;
    }
    __syncthreads();
    #pragma unroll
    for (int k4 = 0; k4 < 16; k4 += 4) {
      float bv0 = Bs[k4+0][n], bv1 = Bs[k4+1][n], bv2 = Bs[k4+2][n], bv3 = Bs[k4+3][n];
      #pragma unroll
      for (int j = 0; j < 32; ++j) {
        float4 a4 = *(const float4*)&As[(wl2*32+j)*16 + k4];
        acc[j] = fmaf(a4.x, bv0, acc[j]);
        acc[j] = fmaf(a4.y, bv1, acc[j]);
        acc[j] = fmaf(a4.z, bv2, acc[j]);
        acc[j] = fmaf(a4.w, bv3, acc[j]);
      }
    }
  }
  int bh128 = ((b<<3)+hd) << 7;
  const float* invrow = type ? invn1w : invn2w;
  const float* invcol = type ? invn2w : invn1h;
  float scol = invcol[bh128 + n];
  #pragma unroll
  for (int j = 0; j < 32; ++j) {
    int row = wl2*32 + j;
    Smat[row*132 + n] = acc[j] * invrow[bh128 + w0 + row] * scol;
  }
  __syncthreads();
  int row = t >> 2, li = t & 3;
  const float4* rp = (const float4*)&Smat[row*132 + li*32];
  float4 v[8];
  float mx = -1e30f;
  #pragma unroll
  for (int q = 0; q < 8; ++q) {
    v[q] = rp[q];
    mx = fmaxf(mx, fmaxf(fmaxf(v[q].x,v[q].y), fmaxf(v[q].z,v[q].w)));
  }
  mx = fmaxf(mx, __shfl_xor(mx, 1));
  mx = fmaxf(mx, __shfl_xor(mx, 2));
  float sum = 0.f;
  #pragma unroll
  for (int q = 0; q < 8; ++q) {
    v[q].x = __expf(v[q].x - mx); v[q].y = __expf(v[q].y - mx);
    v[q].z = __expf(v[q].z - mx); v[q].w = __expf(v[q].w - mx);
    sum += v[q].x+v[q].y+v[q].z+v[q].w;
  }
  sum += __shfl_xor(sum, 1);
  sum += __shfl_xor(sum, 2);
  float inv = 1.f/sum;
  float* Ao = (type ? A2 : A1) + (long)bh128*128 + (w0+row)*128 + li*32;
  #pragma unroll
  for (int q = 0; q < 8; ++q) {
    float4 r; r.x=v[q].x*inv; r.y=v[q].y*inv; r.z=v[q].z*inv; r.w=v[q].w*inv;
    ((float4*)Ao)[q] = r;
  }
}

// ---------------- o34 = A1 @ out1 (over h') + out1*invn1w (q2 term) ----------------
// block: one (b,cc). A staged in 128x16 chunks (8KB) + X chunk (8KB).
__global__ __launch_bounds__(256,2) void k_o3(const float* __restrict__ out1,
    const float* __restrict__ A1, const float* __restrict__ invn1w,
    float* __restrict__ o34)
{
  __shared__ float Ac[128*16];   // [h][k16]
  __shared__ float Xs[16][128];  // [k16][w]
  int bid = blockIdx.x;
  int b = bid >> 7, cc = bid & 127, hd = cc >> 4;
  int t = threadIdx.x;
  int w = t & 127, h0 = (t >> 7) * 64;
  const float* Ag = A1 + (long)((b<<3)+hd)*16384;
  const float* xp = out1 + (long)(b*Cc+cc)*HW;
  float acc[64];
  #pragma unroll
  for (int j = 0; j < 64; ++j) acc[j] = 0.f;
  for (int kc = 0; kc < 8; ++kc) {
    __syncthreads();
    { int e4 = t;        int hh = e4>>2, q = e4&3;
      ((float4*)Ac)[e4] = *(const float4*)&Ag[hh*128 + kc*16 + q*4];
      e4 = t + 256;      hh = e4>>2;     q = e4&3;
      ((float4*)Ac)[e4] = *(const float4*)&Ag[hh*128 + kc*16 + q*4]; }
    { const float4* xsrc = (const float4*)(xp + kc*2048);
      ((float4*)Xs)[t]       = xsrc[t];
      ((float4*)Xs)[t + 256] = xsrc[t + 256]; }
    __syncthreads();
    #pragma unroll
    for (int k4 = 0; k4 < 16; k4 += 4) {
      float x0 = Xs[k4+0][w], x1 = Xs[k4+1][w], x2 = Xs[k4+2][w], x3 = Xs[k4+3][w];
      #pragma unroll
      for (int j = 0; j < 64; ++j) {
        float4 a4 = *(const float4*)&Ac[(h0+j)*16 + k4];
        acc[j] = fmaf(a4.x,x0,fmaf(a4.y,x1,fmaf(a4.z,x2,fmaf(a4.w,x3,acc[j]))));
      }
    }
  }
  float invw = invn1w[(((b<<3)+hd)<<7) + w];
  #pragma unroll
  for (int j = 0; j < 64; ++j) {
    long idx = (long)(b*Cc+cc)*HW + (h0+j)*128 + w;
    o34[idx] = acc[j] + out1[idx]*invw;
  }
}

// ---------------- o34 += out2 @ A2^T (over w') ----------------
__global__ __launch_bounds__(256,2) void k_o4(const float* __restrict__ out2,
    const float* __restrict__ A2, float* o34)
{
  __shared__ float Ac[128*16];   // [w'][k16] chunk of A2 rows
  __shared__ float Xs[128][17];  // [h][k16] padded
  int bid = blockIdx.x;
  int b = bid >> 7, cc = bid & 127, hd = cc >> 4;
  int t = threadIdx.x;
  int h = t & 127, w0 = (t >> 7) * 64;
  const float* Ag = A2 + (long)((b<<3)+hd)*16384;
  const float* xp = out2 + (long)(b*Cc+cc)*HW;
  float acc[64];
  #pragma unroll
  for (int j = 0; j < 64; ++j) acc[j] = 0.f;
  for (int kc = 0; kc < 8; ++kc) {
    __syncthreads();
    { int e4 = t;        int hh = e4>>2, q = e4&3;
      ((float4*)Ac)[e4] = *(const float4*)&Ag[hh*128 + kc*16 + q*4];
      e4 = t + 256;      hh = e4>>2;     q = e4&3;
      ((float4*)Ac)[e4] = *(const float4*)&Ag[hh*128 + kc*16 + q*4]; }
    { int e4 = t; int hh = e4>>2, q = e4&3;
      float4 vv = *(const float4*)&xp[hh*128 + kc*16 + q*4];
      Xs[hh][q*4+0]=vv.x; Xs[hh][q*4+1]=vv.y; Xs[hh][q*4+2]=vv.z; Xs[hh][q*4+3]=vv.w;
      e4 = t + 256; hh = e4>>2; q = e4&3;
      vv = *(const float4*)&xp[hh*128 + kc*16 + q*4];
      Xs[hh][q*4+0]=vv.x; Xs[hh][q*4+1]=vv.y; Xs[hh][q*4+2]=vv.z; Xs[hh][q*4+3]=vv.w; }
    __syncthreads();
    #pragma unroll
    for (int k4 = 0; k4 < 16; k4 += 4) {
      float x0 = Xs[h][k4+0], x1 = Xs[h][k4+1], x2 = Xs[h][k4+2], x3 = Xs[h][k4+3];
      #pragma unroll
      for (int j = 0; j < 64; ++j) {
        float4 a4 = *(const float4*)&Ac[(w0+j)*16 + k4];
        acc[j] = fmaf(a4.x,x0,fmaf(a4.y,x1,fmaf(a4.z,x2,fmaf(a4.w,x3,acc[j]))));
      }
    }
  }
  long base = (long)(b*Cc+cc)*HW + h*128 + w0;
  #pragma unroll
  for (int j = 0; j < 64; j += 4) {
    float4 o = *(float4*)&o34[base + j];
    o.x += acc[j+0]; o.y += acc[j+1]; o.z += acc[j+2]; o.w += acc[j+3];
    *(float4*)&o34[base + j] = o;
  }
}

// ---------------- o34 += out2^T * invn2w (q1 term), 32x32 tiled transpose ----------------
__global__ __launch_bounds__(256) void k_tadd(const float* __restrict__ out2,
    const float* __restrict__ invn2w, float* o34)
{
  __shared__ float Ls[32][33];
  int bid = blockIdx.x;
  int wi = bid & 3, hi = (bid>>2)&3, cc = (bid>>4)&127, b = bid>>11;
  int h0 = hi*32, w0 = wi*32;
  int hd = cc >> 4;
  int t = threadIdx.x;
  int li = t & 31, r0 = t >> 5;
  const float* p = out2 + (long)(b*Cc+cc)*HW;
  for (int r = r0; r < 32; r += 8)
    Ls[r][li] = p[(w0+r)*128 + h0 + li];
  __syncthreads();
  float* q = o34 + (long)(b*Cc+cc)*HW;
  for (int r = r0; r < 32; r += 8) {
    float iv = invn2w[(((b<<3)+hd)<<7) + h0 + r];
    q[(h0+r)*128 + w0 + li] += Ls[li][r] * iv;
  }
}

extern "C" void kernel_launch(void* const* d_in, const int* in_sizes, int n_in,
                              void* d_out, int out_size, void* d_ws, size_t ws_size,
                              hipStream_t stream)
{
  const float* x    = (const float*)d_in[0];
  const float* ln_w = (const float*)d_in[1];
  const float* ln_b = (const float*)d_in[2];
  const float* wd1  = (const float*)d_in[3];
  const float* gd1  = (const float*)d_in[4];
  const float* bd1  = (const float*)d_in[5];
  const float* wd2  = (const float*)d_in[6];
  const float* gd2  = (const float*)d_in[7];
  const float* bd2  = (const float*)d_in[8];
  const float* wd3  = (const float*)d_in[9];
  const float* gd3  = (const float*)d_in[10];
  const float* bd3  = (const float*)d_in[11];
  const float* w_out1 = (const float*)d_in[12];
  const float* w1 = (const float*)d_in[13]; const float* b1 = (const float*)d_in[14];
  const float* w2 = (const float*)d_in[15]; const float* b2 = (const float*)d_in[16];
  const float* w3 = (const float*)d_in[17]; const float* b3 = (const float*)d_in[18];
  const float* w4 = (const float*)d_in[19]; const float* b4 = (const float*)d_in[20];
  const float* w5 = (const float*)d_in[21]; const float* b5 = (const float*)d_in[22];
  const float* w6 = (const float*)d_in[23]; const float* b6 = (const float*)d_in[24];
  const float* w_out2 = (const float*)d_in[25];
  float* out = (float*)d_out;

  const long SLAB = 16777216L;
  float* buf0 = (float*)d_ws;            // x1 -> out1
  float* buf1 = buf0 + SLAB;             // y1 -> s -> o34
  float* buf2 = buf1 + SLAB;             // y2 -> out2
  float* dbuf = out;                     // y3 -> att -> final output
  float* A1 = buf2 + SLAB;
  float* A2 = A1 + 1048576;
  float* stats = A2 + 1048576;
  float* invn1h = stats + 768;
  float* invn1w = invn1h + 8192;
  float* invn2w = invn1w + 8192;
  float* wr2 = invn2w + 8192;
  float* wr3 = wr2 + 147456;
  float* wr1 = wr3 + 147456;
  float* wro1 = wr1 + 16384;
  float* wro2 = wro1 + 16384;

  k_zero<<<3, 256, 0, stream>>>(stats, 768);
  k_reorg<<<576, 256, 0, stream>>>(wd2, wr2);
  k_reorg<<<576, 256, 0, stream>>>(wd3, wr3);
  k_reorg1<<<64, 256, 0, stream>>>(wd1, wr1);
  k_reorg1<<<64, 256, 0, stream>>>(w_out1, wro1);
  k_reorg1<<<64, 256, 0, stream>>>(w_out2, wro2);
  k_ln<<<512, 256, 0, stream>>>(x, ln_w, ln_b, buf0);
  k_conv<<<1024, 256, 0, stream>>>(x, wr1, nullptr, buf1, 1, 1);     // y1
  k_conv<<<1024, 256, 0, stream>>>(x, wr2, nullptr, buf2, 3, 6);     // y2
  k_conv<<<1024, 256, 0, stream>>>(x, wr3, nullptr, dbuf, 3, 12);    // y3 (in d_out)
  k_bnstats<<<3072, 256, 0, stream>>>(buf1, buf2, dbuf, stats);
  k_bnapply<<<16384, 256, 0, stream>>>(buf1, buf2, dbuf, stats,
                                       gd1, bd1, gd2, bd2, gd3, bd3, buf1); // s
  k_conv<<<1024, 256, 0, stream>>>(buf1, wro1, x, buf2, 1, 1);       // out2
  k_dw<<<65536, 256, 0, stream>>>(buf0, w1,b1,w2,b2,w3,b3,w4,b4,w5,b5,w6,b6, dbuf); // att
  k_conv<<<1024, 256, 0, stream>>>(dbuf, wro2, nullptr, buf0, 1, 1); // out1
  k_normh<<<8192, 256, 0, stream>>>(buf0, invn1h);
  k_normw<<<128, 256, 0, stream>>>(buf0, buf2, invn1w, invn2w);
  k_attnS<<<256, 256, 0, stream>>>(buf0, buf2, invn1h, invn1w, invn2w, A1, A2);
  k_o3<<<1024, 256, 0, stream>>>(buf0, A1, invn1w, buf1);            // o34 = A1-part + q2
  k_o4<<<1024, 256, 0, stream>>>(buf2, A2, buf1);                    // += A2-part
  k_tadd<<<16384, 256, 0, stream>>>(buf2, invn2w, buf1);             // += q1 (transposed)
  k_conv<<<1024, 256, 0, stream>>>(buf1, wro2, x, out, 1, 1);        // final + x
}

// Round 3
// 3122.046 us; speedup vs baseline: 1.6574x; 1.6574x over previous
//
#include <hip/hip_runtime.h>

#define Bb 8
#define Cc 128
#define Hh 128
#define Ww 128
#define HW 16384
#define CHW (Cc*HW)
#define NHW (Bb*HW)
#define CH 16
#define EPS 1e-5f

// ---------------- LayerNorm over channel dim ----------------
__global__ __launch_bounds__(256) void k_ln(const float* __restrict__ x,
    const float* __restrict__ g, const float* __restrict__ be,
    float* __restrict__ y)
{
  int p = blockIdx.x*256 + threadIdx.x;     // 0..131071  (b,hw)
  int b = p >> 14, hw = p & 16383;
  const float* xp = x + (long)b*CHW + hw;
  float s = 0.f, q = 0.f;
  for (int c = 0; c < Cc; ++c) { float v = xp[c*HW]; s += v; q += v*v; }
  float mu = s * (1.f/Cc);
  float var = q * (1.f/Cc) - mu*mu;
  float rstd = rsqrtf(var + EPS);
  float* yp = y + (long)b*CHW + hw;
  for (int c = 0; c < Cc; ++c) {
    float v = xp[c*HW];
    yp[c*HW] = (v - mu) * rstd * g[c] + be[c];
  }
}

// ---------------- 3x3 weight reorg: [co][ci][tap] -> [tap][ci*128+co] ----------------
__global__ __launch_bounds__(256) void k_reorg(const float* __restrict__ Wt, float* __restrict__ out)
{
  int idx = blockIdx.x*256 + threadIdx.x;   // < 147456
  int tap = idx >> 14, r = idx & 16383;
  int ci = r >> 7, co = r & 127;
  out[idx] = Wt[(co*128 + ci)*9 + tap];
}

// ---------------- 1x1 weight reorg: [co][ci] -> [ci*128+co] ----------------
__global__ __launch_bounds__(256) void k_reorg1(const float* __restrict__ Wt, float* __restrict__ out)
{
  int idx = blockIdx.x*256 + threadIdx.x;   // < 16384
  int ci = idx >> 7, co = idx & 127;
  out[idx] = Wt[co*128 + ci];
}

__global__ __launch_bounds__(256) void k_zero(float* p, int n)
{
  int i = blockIdx.x*256 + threadIdx.x;
  if (i < n) p[i] = 0.f;
}

// ---------------- dense conv (1x1 or 3x3 dilated). W pre-laid [tap][ci][co] ----------------
// block: 128 co x 128 w (one row h); thread: 8 co x 8 w. LDS: 8KB W-chunk + 8KB X-row.
__global__ __launch_bounds__(256,2) void k_conv(const float* __restrict__ X,
    const float* __restrict__ Wt, const float* __restrict__ res,
    float* __restrict__ Y, int k3, int dil)
{
  __shared__ float Wc[2048];    // [k16][co128]
  __shared__ float Xs[2048];    // [k16][w128]
  int bid = blockIdx.x;
  int b = bid >> 7, h = bid & 127;
  int t = threadIdx.x;
  int co0 = (t & 15) << 3;
  int sp0 = (t >> 4) << 3;
  float acc[8][8];
  #pragma unroll
  for (int i = 0; i < 8; ++i)
    #pragma unroll
    for (int j = 0; j < 8; ++j) acc[i][j] = 0.f;
  int half = k3 >> 1;
  for (int kh = 0; kh < k3; ++kh) {
    int hs = h + (kh - half)*dil;
    if ((unsigned)hs >= (unsigned)Hh) continue;       // block-uniform
    for (int kw = 0; kw < k3; ++kw) {
      int dw = (kw - half)*dil;
      const float* wbase = Wt + (kh*k3 + kw)*16384;
      for (int kc = 0; kc < 8; ++kc) {
        __syncthreads();
        { const float4* wsrc = (const float4*)(wbase + kc*2048);
          ((float4*)Wc)[t]       = wsrc[t];
          ((float4*)Wc)[t + 256] = wsrc[t + 256]; }
        { int cl = t >> 4, wb = (t & 15) << 3;
          const float* sx = X + ((long)(b*Cc + kc*16 + cl)*Hh + hs)*Ww + dw;
          #pragma unroll
          for (int i = 0; i < 8; ++i) {
            int wsrc = wb + i + dw;
            Xs[cl*128 + wb + i] = ((unsigned)wsrc < (unsigned)Ww) ? sx[wb + i] : 0.f;
          }
        }
        __syncthreads();
        #pragma unroll
        for (int k = 0; k < 16; ++k) {
          float4 wa = *(const float4*)&Wc[k*128 + co0];
          float4 wb4 = *(const float4*)&Wc[k*128 + co0 + 4];
          float4 xa = *(const float4*)&Xs[k*128 + sp0];
          float4 xb = *(const float4*)&Xs[k*128 + sp0 + 4];
          float wv[8] = {wa.x,wa.y,wa.z,wa.w,wb4.x,wb4.y,wb4.z,wb4.w};
          float xv[8] = {xa.x,xa.y,xa.z,xa.w,xb.x,xb.y,xb.z,xb.w};
          #pragma unroll
          for (int i = 0; i < 8; ++i)
            #pragma unroll
            for (int j = 0; j < 8; ++j)
              acc[i][j] = fmaf(wv[i], xv[j], acc[i][j]);
        }
      }
    }
  }
  #pragma unroll
  for (int i = 0; i < 8; ++i) {
    long idx = ((long)(b*Cc + co0 + i)*Hh + h)*Ww + sp0;
    float4 r0, r1;
    r0.x=acc[i][0]; r0.y=acc[i][1]; r0.z=acc[i][2]; r0.w=acc[i][3];
    r1.x=acc[i][4]; r1.y=acc[i][5]; r1.z=acc[i][6]; r1.w=acc[i][7];
    if (res) {
      float4 a = *(const float4*)&res[idx];
      float4 bv = *(const float4*)&res[idx+4];
      r0.x+=a.x; r0.y+=a.y; r0.z+=a.z; r0.w+=a.w;
      r1.x+=bv.x; r1.y+=bv.y; r1.z+=bv.z; r1.w+=bv.w;
    }
    *(float4*)&Y[idx] = r0;
    *(float4*)&Y[idx+4] = r1;
  }
}

// ---------------- BN batch stats (sum, sumsq per channel, 3 tensors) ----------------
__global__ __launch_bounds__(256) void k_bnstats(const float* __restrict__ y1,
    const float* __restrict__ y2, const float* __restrict__ y3,
    float* __restrict__ stats)
{
  __shared__ float red[512];
  int bid = blockIdx.x;                 // 3*128*8
  int tsel = bid >> 10;
  int rem = bid & 1023;
  int c = rem >> 3, b = rem & 7;
  const float* y = tsel == 0 ? y1 : (tsel == 1 ? y2 : y3);
  const float* p = y + (long)(b*Cc + c)*HW;
  float s = 0.f, q = 0.f;
  for (int i = threadIdx.x; i < HW; i += 256) { float v = p[i]; s += v; q += v*v; }
  red[threadIdx.x] = s; red[256+threadIdx.x] = q;
  __syncthreads();
  for (int st = 128; st > 0; st >>= 1) {
    if (threadIdx.x < st) {
      red[threadIdx.x] += red[threadIdx.x+st];
      red[256+threadIdx.x] += red[256+threadIdx.x+st];
    }
    __syncthreads();
  }
  if (threadIdx.x == 0) {
    atomicAdd(&stats[tsel*256 + c], red[0]);
    atomicAdd(&stats[tsel*256 + 128 + c], red[256]);
  }
}

// ---------------- BN apply + relu, sum three branches ----------------
__global__ __launch_bounds__(256) void k_bnapply(const float* y1,
    const float* __restrict__ y2, const float* __restrict__ y3,
    const float* __restrict__ stats,
    const float* __restrict__ g1, const float* __restrict__ be1,
    const float* __restrict__ g2, const float* __restrict__ be2,
    const float* __restrict__ g3, const float* __restrict__ be3,
    float* out)
{
  int i4 = blockIdx.x*256 + threadIdx.x;   // float4 index
  int c = (i4 >> 12) & 127;
  const float inv = 1.f/(float)NHW;
  float mu1 = stats[c]*inv;       float v1 = stats[128+c]*inv - mu1*mu1;
  float mu2 = stats[256+c]*inv;   float v2 = stats[384+c]*inv - mu2*mu2;
  float mu3 = stats[512+c]*inv;   float v3 = stats[640+c]*inv - mu3*mu3;
  float s1 = rsqrtf(v1+EPS)*g1[c], s2 = rsqrtf(v2+EPS)*g2[c], s3 = rsqrtf(v3+EPS)*g3[c];
  float o1 = be1[c]-mu1*s1, o2 = be2[c]-mu2*s2, o3_ = be3[c]-mu3*s3;
  float4 a = ((const float4*)y1)[i4];
  float4 bq = ((const float4*)y2)[i4];
  float4 cq = ((const float4*)y3)[i4];
  float4 r;
  r.x = fmaxf(fmaf(a.x,s1,o1),0.f)+fmaxf(fmaf(bq.x,s2,o2),0.f)+fmaxf(fmaf(cq.x,s3,o3_),0.f);
  r.y = fmaxf(fmaf(a.y,s1,o1),0.f)+fmaxf(fmaf(bq.y,s2,o2),0.f)+fmaxf(fmaf(cq.y,s3,o3_),0.f);
  r.z = fmaxf(fmaf(a.z,s1,o1),0.f)+fmaxf(fmaf(bq.z,s2,o2),0.f)+fmaxf(fmaf(cq.z,s3,o3_),0.f);
  r.w = fmaxf(fmaf(a.w,s1,o1),0.f)+fmaxf(fmaf(bq.w,s2,o2),0.f)+fmaxf(fmaf(cq.w,s3,o3_),0.f);
  ((float4*)out)[i4] = r;
}

// ---------------- six depthwise branches summed (with biases) ----------------
__global__ __launch_bounds__(256) void k_dw(const float* __restrict__ X,
    const float* __restrict__ w1, const float* __restrict__ b1,
    const float* __restrict__ w2, const float* __restrict__ b2,
    const float* __restrict__ w3, const float* __restrict__ b3,
    const float* __restrict__ w4, const float* __restrict__ b4,
    const float* __restrict__ w5, const float* __restrict__ b5,
    const float* __restrict__ w6, const float* __restrict__ b6,
    float* __restrict__ Y)
{
  int lin = blockIdx.x*256 + threadIdx.x;
  int w = lin & 127, h = (lin>>7)&127, c = (lin>>14)&127;
  float hcoef[7], vcoef[7];
  #pragma unroll
  for (int d = 0; d < 7; ++d) { hcoef[d] = w5[c*7+d]; vcoef[d] = w6[c*7+d]; }
  #pragma unroll
  for (int d = 1; d < 6; ++d) { hcoef[d] += w1[c*5+d-1]; vcoef[d] += w2[c*5+d-1]; }
  hcoef[3] += w3[c];
  float acc = b1[c]+b2[c]+b3[c]+b4[c]+b5[c]+b6[c];
  const float* xp = X + ((long)lin >> 14 << 14);   // base of (b,c) slab
  #pragma unroll
  for (int d = 0; d < 7; ++d) {
    int wq = w + d - 3;
    if ((unsigned)wq < 128u) acc = fmaf(hcoef[d], xp[h*128 + wq], acc);
    int hq = h + d - 3;
    if ((unsigned)hq < 128u) acc = fmaf(vcoef[d], xp[hq*128 + w], acc);
  }
  #pragma unroll
  for (int kh = 0; kh < 3; ++kh) {
    int hq = h + kh - 1;
    if ((unsigned)hq >= 128u) continue;
    #pragma unroll
    for (int kw = 0; kw < 3; ++kw) {
      int wq = w + kw - 1;
      if ((unsigned)wq < 128u) acc = fmaf(w4[c*9+kh*3+kw], xp[hq*128+wq], acc);
    }
  }
  Y[lin] = acc;
}

// ---------------- norms ----------------
__global__ __launch_bounds__(256) void k_normh(const float* __restrict__ out1, float* __restrict__ invn)
{
  __shared__ float red[256];
  int bid = blockIdx.x;                // (b*8+hd)*128 + h
  int h = bid & 127; int bh = bid >> 7;
  int b = bh >> 3, hd = bh & 7;
  const float* p = out1 + ((long)(b*Cc + hd*CH)*Hh + h)*Ww;
  float s = 0.f;
  for (int e = threadIdx.x; e < 2048; e += 256) {
    int c = e >> 7, w = e & 127;
    float v = p[(long)c*HW + w];
    s += v*v;
  }
  red[threadIdx.x] = s; __syncthreads();
  for (int st = 128; st > 0; st >>= 1) {
    if (threadIdx.x < st) red[threadIdx.x] += red[threadIdx.x+st];
    __syncthreads();
  }
  if (threadIdx.x == 0) invn[bid] = 1.f/fmaxf(sqrtf(red[0]), 1e-12f);
}

__global__ __launch_bounds__(256) void k_normw(const float* __restrict__ out1,
    const float* __restrict__ out2, float* __restrict__ invn1w, float* __restrict__ invn2w)
{
  __shared__ float red[256];
  int bid = blockIdx.x;
  int tsel = bid & 1; int bh = bid >> 1; int b = bh >> 3, hd = bh & 7;
  const float* src = tsel ? out2 : out1;
  int t = threadIdx.x;
  int w = t & 127, half = t >> 7;
  const float* p = src + (long)(b*Cc + hd*CH)*HW + w;
  float s = 0.f;
  for (int c = 0; c < CH; ++c)
    for (int h = half; h < 128; h += 2) {
      float v = p[(long)c*HW + h*128];
      s += v*v;
    }
  red[t] = s; __syncthreads();
  if (t < 128) {
    float tot = red[t] + red[t+128];
    float iv = 1.f/fmaxf(sqrtf(tot), 1e-12f);
    (tsel ? invn2w : invn1w)[bh*128 + w] = iv;
  }
}

// ---------------- S = scaled cross-products + softmax -> A1/A2 ----------------
// grid: type(2) x b(8) x hd(8) x wtile(2); block computes S[64w x 128n], K=2048
__global__ __launch_bounds__(256,2) void k_attnS(const float* __restrict__ out1,
    const float* __restrict__ out2, const float* __restrict__ invn1h,
    const float* __restrict__ invn1w, const float* __restrict__ invn2w,
    float* __restrict__ A1, float* __restrict__ A2)
{
  __shared__ float As[64*16];
  __shared__ float Bs[16][128];
  __shared__ float Smat[64*132];
  int bid = blockIdx.x;
  int wt = bid & 1, hd = (bid>>1)&7, b = (bid>>4)&7, type = bid>>7;
  int w0 = wt*64;
  int t = threadIdx.x;
  int n = t & 127, wl2 = t >> 7;
  const float* srcA = type ? out1 : out2;
  const float* srcB = type ? out2 : out1;
  long slab = (long)(b*Cc + hd*CH)*HW;
  float acc[32];
  #pragma unroll
  for (int j = 0; j < 32; ++j) acc[j] = 0.f;
  for (int kc = 0; kc < 128; ++kc) {
    int cci = kc >> 3;
    int in0 = (kc & 7) << 4;
    const float* pa = srcA + slab + (long)cci*HW;
    const float* pb = srcB + slab + (long)cci*HW;
    __syncthreads();
    for (int e = t; e < 1024; e += 256) {       // As[wl][kl]
      int kl = e >> 6, wl = e & 63;
      As[wl*16 + kl] = pa[(in0+kl)*128 + w0 + wl];
    }
    if (type) {                                  // Bs[kl][n'] = pb[(in0+kl)*128+n']
      for (int e = t; e < 512; e += 256) {
        int kl = e >> 5, q = e & 31;
        *(float4*)&Bs[kl][q*4] = *(const float4*)&pb[(in0+kl)*128 + q*4];
      }
    } else {                                     // Bs[kl][n'] = pb[n'*128+in0+kl] (transpose)
      int nn = t >> 1, pq = t & 1;
      float4 v0 = *(const float4*)&pb[nn*128 + in0 + pq*4];
      float4 v1 = *(const float4*)&pb[nn*128 + in0 + 8 + pq*4];
      Bs[pq*4+0][nn] = v0.x; Bs[pq*4+1][nn] = v0.y;
      Bs[pq*4+2][nn] = v0.z; Bs[pq*4+3][nn] = v0.w;
      Bs[8+pq*4+0][nn] = v1.x; Bs[8+pq*4+1][nn] = v1.y;
      Bs[8+pq*4+2][nn] = v1.z; Bs[8+pq*4+3][nn] = v1.w;
    }
    __syncthreads();
    #pragma unroll
    for (int k4 = 0; k4 < 16; k4 += 4) {
      float bv0 = Bs[k4+0][n], bv1 = Bs[k4+1][n], bv2 = Bs[k4+2][n], bv3 = Bs[k4+3][n];
      #pragma unroll
      for (int j = 0; j < 32; ++j) {
        float4 a4 = *(const float4*)&As[(wl2*32+j)*16 + k4];
        acc[j] = fmaf(a4.x, bv0, acc[j]);
        acc[j] = fmaf(a4.y, bv1, acc[j]);
        acc[j] = fmaf(a4.z, bv2, acc[j]);
        acc[j] = fmaf(a4.w, bv3, acc[j]);
      }
    }
  }
  int bh128 = ((b<<3)+hd) << 7;
  const float* invrow = type ? invn1w : invn2w;
  const float* invcol = type ? invn2w : invn1h;
  float scol = invcol[bh128 + n];
  #pragma unroll
  for (int j = 0; j < 32; ++j) {
    int row = wl2*32 + j;
    Smat[row*132 + n] = acc[j] * invrow[bh128 + w0 + row] * scol;
  }
  __syncthreads();
  int row = t >> 2, li = t & 3;
  const float4* rp = (const float4*)&Smat[row*132 + li*32];
  float4 v[8];
  float mx = -1e30f;
  #pragma unroll
  for (int q = 0; q < 8; ++q) {
    v[q] = rp[q];
    mx = fmaxf(mx, fmaxf(fmaxf(v[q].x,v[q].y), fmaxf(v[q].z,v[q].w)));
  }
  mx = fmaxf(mx, __shfl_xor(mx, 1));
  mx = fmaxf(mx, __shfl_xor(mx, 2));
  float sum = 0.f;
  #pragma unroll
  for (int q = 0; q < 8; ++q) {
    v[q].x = __expf(v[q].x - mx); v[q].y = __expf(v[q].y - mx);
    v[q].z = __expf(v[q].z - mx); v[q].w = __expf(v[q].w - mx);
    sum += v[q].x+v[q].y+v[q].z+v[q].w;
  }
  sum += __shfl_xor(sum, 1);
  sum += __shfl_xor(sum, 2);
  float inv = 1.f/sum;
  float* Ao = (type ? A2 : A1) + (long)bh128*128 + (w0+row)*128 + li*32;
  #pragma unroll
  for (int q = 0; q < 8; ++q) {
    float4 r; r.x=v[q].x*inv; r.y=v[q].y*inv; r.z=v[q].z*inv; r.w=v[q].w*inv;
    ((float4*)Ao)[q] = r;
  }
}

// ---------------- o34 = A1 @ out1 (over h') + out1*invn1w (q2 term) ----------------
// k_conv-style register tile: block = (b,cc), 128h x 128w out, thread 8x8, acc[8][8].
// o3[h][w] = sum_k A1[h][k] * out1slab[k][w]
__global__ __launch_bounds__(256,2) void k_o3(const float* __restrict__ out1,
    const float* __restrict__ A1, const float* __restrict__ invn1w,
    float* __restrict__ o34)
{
  __shared__ float Ac[2048];     // [k16][h128]  (A1 chunk, transposed)
  __shared__ float Xs[2048];     // [k16][w128]
  int bid = blockIdx.x;
  int b = bid >> 7, cc = bid & 127, hd = cc >> 4;
  int t = threadIdx.x;
  int h0 = (t & 15) << 3;
  int w0 = (t >> 4) << 3;
  const float* Ag = A1 + (long)((b<<3)+hd)*16384;
  const float* xp = out1 + (long)(b*Cc+cc)*HW;
  float acc[8][8];
  #pragma unroll
  for (int i = 0; i < 8; ++i)
    #pragma unroll
    for (int j = 0; j < 8; ++j) acc[i][j] = 0.f;
  for (int kc = 0; kc < 8; ++kc) {
    __syncthreads();
    { // Ac[k][h] = Ag[h*128 + kc*16 + k]  (transpose scatter, float4 loads)
      int e = t;
      #pragma unroll
      for (int r = 0; r < 2; ++r, e += 256) {
        int hh = e >> 2, q = e & 3;
        float4 v = *(const float4*)&Ag[hh*128 + kc*16 + q*4];
        Ac[(q*4+0)*128 + hh] = v.x;
        Ac[(q*4+1)*128 + hh] = v.y;
        Ac[(q*4+2)*128 + hh] = v.z;
        Ac[(q*4+3)*128 + hh] = v.w;
      }
    }
    { const float4* xsrc = (const float4*)(xp + kc*2048);
      ((float4*)Xs)[t]       = xsrc[t];
      ((float4*)Xs)[t + 256] = xsrc[t + 256]; }
    __syncthreads();
    #pragma unroll
    for (int k = 0; k < 16; ++k) {
      float4 aa = *(const float4*)&Ac[k*128 + h0];
      float4 ab = *(const float4*)&Ac[k*128 + h0 + 4];
      float4 xa = *(const float4*)&Xs[k*128 + w0];
      float4 xb = *(const float4*)&Xs[k*128 + w0 + 4];
      float av[8] = {aa.x,aa.y,aa.z,aa.w,ab.x,ab.y,ab.z,ab.w};
      float xv[8] = {xa.x,xa.y,xa.z,xa.w,xb.x,xb.y,xb.z,xb.w};
      #pragma unroll
      for (int i = 0; i < 8; ++i)
        #pragma unroll
        for (int j = 0; j < 8; ++j)
          acc[i][j] = fmaf(av[i], xv[j], acc[i][j]);
    }
  }
  int bh128 = ((b<<3)+hd) << 7;
  float4 iva = *(const float4*)&invn1w[bh128 + w0];
  float4 ivb = *(const float4*)&invn1w[bh128 + w0 + 4];
  float iv[8] = {iva.x,iva.y,iva.z,iva.w,ivb.x,ivb.y,ivb.z,ivb.w};
  #pragma unroll
  for (int i = 0; i < 8; ++i) {
    long idx = (long)(b*Cc+cc)*HW + (h0+i)*128 + w0;
    float4 u0 = *(const float4*)&xp[(h0+i)*128 + w0];
    float4 u1 = *(const float4*)&xp[(h0+i)*128 + w0 + 4];
    float4 r0, r1;
    r0.x = acc[i][0] + u0.x*iv[0]; r0.y = acc[i][1] + u0.y*iv[1];
    r0.z = acc[i][2] + u0.z*iv[2]; r0.w = acc[i][3] + u0.w*iv[3];
    r1.x = acc[i][4] + u1.x*iv[4]; r1.y = acc[i][5] + u1.y*iv[5];
    r1.z = acc[i][6] + u1.z*iv[6]; r1.w = acc[i][7] + u1.w*iv[7];
    *(float4*)&o34[idx] = r0;
    *(float4*)&o34[idx+4] = r1;
  }
}

// ---------------- o34 += out2 @ A2^T (over w') ----------------
// o4[h][w] = sum_k out2slab[h][k] * A2[w][k]; both operands transposed-staged.
__global__ __launch_bounds__(256,2) void k_o4(const float* __restrict__ out2,
    const float* __restrict__ A2, float* o34)
{
  __shared__ float Xk[2048];     // [k16][h128]  (out2 chunk, transposed)
  __shared__ float An[2048];     // [k16][w128]  (A2 chunk, transposed)
  int bid = blockIdx.x;
  int b = bid >> 7, cc = bid & 127, hd = cc >> 4;
  int t = threadIdx.x;
  int h0 = (t & 15) << 3;
  int w0 = (t >> 4) << 3;
  const float* Ag = A2 + (long)((b<<3)+hd)*16384;
  const float* xp = out2 + (long)(b*Cc+cc)*HW;
  float acc[8][8];
  #pragma unroll
  for (int i = 0; i < 8; ++i)
    #pragma unroll
    for (int j = 0; j < 8; ++j) acc[i][j] = 0.f;
  for (int kc = 0; kc < 8; ++kc) {
    __syncthreads();
    { int e = t;
      #pragma unroll
      for (int r = 0; r < 2; ++r, e += 256) {
        int hh = e >> 2, q = e & 3;
        float4 v = *(const float4*)&xp[hh*128 + kc*16 + q*4];
        Xk[(q*4+0)*128 + hh] = v.x;
        Xk[(q*4+1)*128 + hh] = v.y;
        Xk[(q*4+2)*128 + hh] = v.z;
        Xk[(q*4+3)*128 + hh] = v.w;
      }
    }
    { int e = t;
      #pragma unroll
      for (int r = 0; r < 2; ++r, e += 256) {
        int ww = e >> 2, q = e & 3;
        float4 v = *(const float4*)&Ag[ww*128 + kc*16 + q*4];
        An[(q*4+0)*128 + ww] = v.x;
        An[(q*4+1)*128 + ww] = v.y;
        An[(q*4+2)*128 + ww] = v.z;
        An[(q*4+3)*128 + ww] = v.w;
      }
    }
    __syncthreads();
    #pragma unroll
    for (int k = 0; k < 16; ++k) {
      float4 aa = *(const float4*)&Xk[k*128 + h0];
      float4 ab = *(const float4*)&Xk[k*128 + h0 + 4];
      float4 xa = *(const float4*)&An[k*128 + w0];
      float4 xb = *(const float4*)&An[k*128 + w0 + 4];
      float av[8] = {aa.x,aa.y,aa.z,aa.w,ab.x,ab.y,ab.z,ab.w};
      float xv[8] = {xa.x,xa.y,xa.z,xa.w,xb.x,xb.y,xb.z,xb.w};
      #pragma unroll
      for (int i = 0; i < 8; ++i)
        #pragma unroll
        for (int j = 0; j < 8; ++j)
          acc[i][j] = fmaf(av[i], xv[j], acc[i][j]);
    }
  }
  #pragma unroll
  for (int i = 0; i < 8; ++i) {
    long idx = (long)(b*Cc+cc)*HW + (h0+i)*128 + w0;
    float4 r0 = *(const float4*)&o34[idx];
    float4 r1 = *(const float4*)&o34[idx+4];
    r0.x += acc[i][0]; r0.y += acc[i][1]; r0.z += acc[i][2]; r0.w += acc[i][3];
    r1.x += acc[i][4]; r1.y += acc[i][5]; r1.z += acc[i][6]; r1.w += acc[i][7];
    *(float4*)&o34[idx] = r0;
    *(float4*)&o34[idx+4] = r1;
  }
}

// ---------------- o34 += out2^T * invn2w (q1 term), 32x32 tiled transpose ----------------
__global__ __launch_bounds__(256) void k_tadd(const float* __restrict__ out2,
    const float* __restrict__ invn2w, float* o34)
{
  __shared__ float Ls[32][33];
  int bid = blockIdx.x;
  int wi = bid & 3, hi = (bid>>2)&3, cc = (bid>>4)&127, b = bid>>11;
  int h0 = hi*32, w0 = wi*32;
  int hd = cc >> 4;
  int t = threadIdx.x;
  int li = t & 31, r0 = t >> 5;
  const float* p = out2 + (long)(b*Cc+cc)*HW;
  for (int r = r0; r < 32; r += 8)
    Ls[r][li] = p[(w0+r)*128 + h0 + li];
  __syncthreads();
  float* q = o34 + (long)(b*Cc+cc)*HW;
  for (int r = r0; r < 32; r += 8) {
    float iv = invn2w[(((b<<3)+hd)<<7) + h0 + r];
    q[(h0+r)*128 + w0 + li] += Ls[li][r] * iv;
  }
}

extern "C" void kernel_launch(void* const* d_in, const int* in_sizes, int n_in,
                              void* d_out, int out_size, void* d_ws, size_t ws_size,
                              hipStream_t stream)
{
  const float* x    = (const float*)d_in[0];
  const float* ln_w = (const float*)d_in[1];
  const float* ln_b = (const float*)d_in[2];
  const float* wd1  = (const float*)d_in[3];
  const float* gd1  = (const float*)d_in[4];
  const float* bd1  = (const float*)d_in[5];
  const float* wd2  = (const float*)d_in[6];
  const float* gd2  = (const float*)d_in[7];
  const float* bd2  = (const float*)d_in[8];
  const float* wd3  = (const float*)d_in[9];
  const float* gd3  = (const float*)d_in[10];
  const float* bd3  = (const float*)d_in[11];
  const float* w_out1 = (const float*)d_in[12];
  const float* w1 = (const float*)d_in[13]; const float* b1 = (const float*)d_in[14];
  const float* w2 = (const float*)d_in[15]; const float* b2 = (const float*)d_in[16];
  const float* w3 = (const float*)d_in[17]; const float* b3 = (const float*)d_in[18];
  const float* w4 = (const float*)d_in[19]; const float* b4 = (const float*)d_in[20];
  const float* w5 = (const float*)d_in[21]; const float* b5 = (const float*)d_in[22];
  const float* w6 = (const float*)d_in[23]; const float* b6 = (const float*)d_in[24];
  const float* w_out2 = (const float*)d_in[25];
  float* out = (float*)d_out;

  const long SLAB = 16777216L;
  float* buf0 = (float*)d_ws;            // x1 -> out1
  float* buf1 = buf0 + SLAB;             // y1 -> s -> o34
  float* buf2 = buf1 + SLAB;             // y2 -> out2
  float* dbuf = out;                     // y3 -> att -> final output
  float* A1 = buf2 + SLAB;
  float* A2 = A1 + 1048576;
  float* stats = A2 + 1048576;
  float* invn1h = stats + 768;
  float* invn1w = invn1h + 8192;
  float* invn2w = invn1w + 8192;
  float* wr2 = invn2w + 8192;
  float* wr3 = wr2 + 147456;
  float* wr1 = wr3 + 147456;
  float* wro1 = wr1 + 16384;
  float* wro2 = wro1 + 16384;

  k_zero<<<3, 256, 0, stream>>>(stats, 768);
  k_reorg<<<576, 256, 0, stream>>>(wd2, wr2);
  k_reorg<<<576, 256, 0, stream>>>(wd3, wr3);
  k_reorg1<<<64, 256, 0, stream>>>(wd1, wr1);
  k_reorg1<<<64, 256, 0, stream>>>(w_out1, wro1);
  k_reorg1<<<64, 256, 0, stream>>>(w_out2, wro2);
  k_ln<<<512, 256, 0, stream>>>(x, ln_w, ln_b, buf0);
  k_conv<<<1024, 256, 0, stream>>>(x, wr1, nullptr, buf1, 1, 1);     // y1
  k_conv<<<1024, 256, 0, stream>>>(x, wr2, nullptr, buf2, 3, 6);     // y2
  k_conv<<<1024, 256, 0, stream>>>(x, wr3, nullptr, dbuf, 3, 12);    // y3 (in d_out)
  k_bnstats<<<3072, 256, 0, stream>>>(buf1, buf2, dbuf, stats);
  k_bnapply<<<16384, 256, 0, stream>>>(buf1, buf2, dbuf, stats,
                                       gd1, bd1, gd2, bd2, gd3, bd3, buf1); // s
  k_conv<<<1024, 256, 0, stream>>>(buf1, wro1, x, buf2, 1, 1);       // out2
  k_dw<<<65536, 256, 0, stream>>>(buf0, w1,b1,w2,b2,w3,b3,w4,b4,w5,b5,w6,b6, dbuf); // att
  k_conv<<<1024, 256, 0, stream>>>(dbuf, wro2, nullptr, buf0, 1, 1); // out1
  k_normh<<<8192, 256, 0, stream>>>(buf0, invn1h);
  k_normw<<<128, 256, 0, stream>>>(buf0, buf2, invn1w, invn2w);
  k_attnS<<<256, 256, 0, stream>>>(buf0, buf2, invn1h, invn1w, invn2w, A1, A2);
  k_o3<<<1024, 256, 0, stream>>>(buf0, A1, invn1w, buf1);            // o34 = A1-part + q2
  k_o4<<<1024, 256, 0, stream>>>(buf2, A2, buf1);                    // += A2-part
  k_tadd<<<16384, 256, 0, stream>>>(buf2, invn2w, buf1);             // += q1 (transposed)
  k_conv<<<1024, 256, 0, stream>>>(buf1, wro2, x, out, 1, 1);        // final + x
}

// Round 4
// 2078.693 us; speedup vs baseline: 2.4893x; 1.5019x over previous
//
#include <hip/hip_runtime.h>

#define Bb 8
#define Cc 128
#define Hh 128
#define Ww 128
#define HW 16384
#define CHW (Cc*HW)
#define NHW (Bb*HW)
#define CH 16
#define EPS 1e-5f

typedef __attribute__((ext_vector_type(8))) short bf16x8;
typedef __attribute__((ext_vector_type(4))) float f32x4;

static __device__ __forceinline__ short f2b(float f) {
  unsigned u = __float_as_uint(f);
  unsigned lsb = (u >> 16) & 1;
  return (short)((u + 0x7fffu + lsb) >> 16);
}

// ---------------- LayerNorm over channel dim ----------------
__global__ __launch_bounds__(256) void k_ln(const float* __restrict__ x,
    const float* __restrict__ g, const float* __restrict__ be,
    float* __restrict__ y)
{
  int p = blockIdx.x*256 + threadIdx.x;     // (b,hw)
  int b = p >> 14, hw = p & 16383;
  const float* xp = x + (long)b*CHW + hw;
  float s = 0.f, q = 0.f;
  for (int c = 0; c < Cc; ++c) { float v = xp[c*HW]; s += v; q += v*v; }
  float mu = s * (1.f/Cc);
  float var = q * (1.f/Cc) - mu*mu;
  float rstd = rsqrtf(var + EPS);
  float* yp = y + (long)b*CHW + hw;
  for (int c = 0; c < Cc; ++c) {
    float v = xp[c*HW];
    yp[c*HW] = (v - mu) * rstd * g[c] + be[c];
  }
}

// ---------------- 3x3 weight: [co][ci][tap] fp32 -> [tap][co][ci] bf16 ----------------
__global__ __launch_bounds__(256) void k_reorg3b(const float* __restrict__ Wt, short* __restrict__ out)
{
  int idx = blockIdx.x*256 + threadIdx.x;   // < 147456
  int tap = idx >> 14, r = idx & 16383;     // r = co*128+ci
  out[idx] = f2b(Wt[r*9 + tap]);
}

// ---------------- 1x1 weight: [co][ci] fp32 -> bf16 (same order) ----------------
__global__ __launch_bounds__(256) void k_cast(const float* __restrict__ in, short* __restrict__ out)
{
  int i = blockIdx.x*256 + threadIdx.x;     // 16384
  out[i] = f2b(in[i]);
}

__global__ __launch_bounds__(256) void k_zero(float* p, int n)
{
  int i = blockIdx.x*256 + threadIdx.x;
  if (i < n) p[i] = 0.f;
}

// ---------------- NCHW fp32 -> NHWC bf16 transpose ----------------
// grid: b(8) x c4(4) x hwt(512); 32c x 32hw tile
__global__ __launch_bounds__(256) void k_nhwc(const float* __restrict__ in, short* __restrict__ out)
{
  __shared__ float Ls[32][33];
  int bid = blockIdx.x;
  int hwt = bid & 511, c4 = (bid>>9)&3, b = bid>>11;
  int hw0 = hwt << 5, c0 = c4 << 5;
  int t = threadIdx.x;
  int hl = t & 31, cl = t >> 5;
  const float* p = in + (long)b*CHW + hw0;
  for (int r = cl; r < 32; r += 8)
    Ls[r][hl] = p[(long)(c0+r)*HW + hl];
  __syncthreads();
  short* q = out + ((long)b*HW + hw0)*Cc + c0;
  int ccl = t & 31, hl0 = t >> 5;
  for (int r = hl0; r < 32; r += 8)
    q[(long)r*Cc + ccl] = f2b(Ls[ccl][r]);
}

// ---------------- MFMA conv (1x1 or dilated 3x3) ----------------
// X: bf16 NHWC [b][h][w][c]; W: bf16 [tap][co][ci]; Y: fp32 NCHW (+res).
// block = (b,h): 128co x 128w tile, 4 waves each 64x64 (4x4 MFMA 16x16x32 tiles).
__global__ __launch_bounds__(256,2) void k_mconv(const short* __restrict__ X,
    const short* __restrict__ W, const float* __restrict__ res,
    float* __restrict__ Y, int k3, int dil)
{
  __shared__ short Ws[128*40];   // [co][ci32 pad40]
  __shared__ short Xt[128*40];   // [sp][ci32 pad40]
  int b = blockIdx.x >> 7, h = blockIdx.x & 127;
  int t = threadIdx.x;
  int wave = t >> 6, lane = t & 63;
  int co0 = (wave >> 1) << 6, sp0 = (wave & 1) << 6;
  int lm = lane & 15, quad = lane >> 4;
  f32x4 acc[4][4];
  #pragma unroll
  for (int i = 0; i < 4; ++i)
    #pragma unroll
    for (int j = 0; j < 4; ++j) acc[i][j] = (f32x4){0.f,0.f,0.f,0.f};
  int half = k3 >> 1;
  int sco = t >> 1, spart = t & 1;          // staging: row + 16-elem half
  for (int kh = 0; kh < k3; ++kh) {
    int hs = h + (kh - half)*dil;
    if ((unsigned)hs >= (unsigned)Hh) continue;     // block-uniform
    for (int kw = 0; kw < k3; ++kw) {
      int dw = (kw - half)*dil;
      const short* wt = W + (kh*k3 + kw)*16384;
      const short* xr = X + ((long)(b*Hh + hs)*Ww)*Cc;
      int wsrc = sco + dw;
      bool inb = (unsigned)wsrc < (unsigned)Ww;
      for (int kc = 0; kc < 4; ++kc) {
        int k0 = kc << 5;
        __syncthreads();
        { // W chunk: 128co x 32ci, 16 bf16/thread
          float4 a0 = *(const float4*)(wt + sco*128 + k0 + spart*16);
          float4 a1 = *(const float4*)(wt + sco*128 + k0 + spart*16 + 8);
          *(float4*)(Ws + sco*40 + spart*16) = a0;
          *(float4*)(Ws + sco*40 + spart*16 + 8) = a1;
        }
        { // X chunk: 128sp x 32ci (NHWC: ci contiguous)
          float4 x0 = {0.f,0.f,0.f,0.f}, x1 = {0.f,0.f,0.f,0.f};
          if (inb) {
            x0 = *(const float4*)(xr + (long)wsrc*Cc + k0 + spart*16);
            x1 = *(const float4*)(xr + (long)wsrc*Cc + k0 + spart*16 + 8);
          }
          *(float4*)(Xt + sco*40 + spart*16) = x0;
          *(float4*)(Xt + sco*40 + spart*16 + 8) = x1;
        }
        __syncthreads();
        bf16x8 af[4], bfr[4];
        #pragma unroll
        for (int i = 0; i < 4; ++i)
          af[i] = *(const bf16x8*)(Ws + (co0 + i*16 + lm)*40 + quad*8);
        #pragma unroll
        for (int j = 0; j < 4; ++j)
          bfr[j] = *(const bf16x8*)(Xt + (sp0 + j*16 + lm)*40 + quad*8);
        #pragma unroll
        for (int i = 0; i < 4; ++i)
          #pragma unroll
          for (int j = 0; j < 4; ++j)
            acc[i][j] = __builtin_amdgcn_mfma_f32_16x16x32_bf16(af[i], bfr[j], acc[i][j], 0, 0, 0);
      }
    }
  }
  // epilogue: C/D col=lane&15 (w), row=quad*4+reg (co)
  #pragma unroll
  for (int i = 0; i < 4; ++i) {
    int co = co0 + i*16 + quad*4;
    #pragma unroll
    for (int j = 0; j < 4; ++j) {
      int wc = sp0 + j*16 + lm;
      long base = ((long)(b*Cc + co)*Hh + h)*Ww + wc;
      #pragma unroll
      for (int r = 0; r < 4; ++r) {
        float v = acc[i][j][r];
        long idx = base + (long)r*HW;
        if (res) v += res[idx];
        Y[idx] = v;
      }
    }
  }
}

// ---------------- BN batch stats ----------------
__global__ __launch_bounds__(256) void k_bnstats(const float* __restrict__ y1,
    const float* __restrict__ y2, const float* __restrict__ y3,
    float* __restrict__ stats)
{
  __shared__ float red[512];
  int bid = blockIdx.x;
  int tsel = bid >> 10;
  int rem = bid & 1023;
  int c = rem >> 3, b = rem & 7;
  const float* y = tsel == 0 ? y1 : (tsel == 1 ? y2 : y3);
  const float* p = y + (long)(b*Cc + c)*HW;
  float s = 0.f, q = 0.f;
  for (int i = threadIdx.x; i < HW; i += 256) { float v = p[i]; s += v; q += v*v; }
  red[threadIdx.x] = s; red[256+threadIdx.x] = q;
  __syncthreads();
  for (int st = 128; st > 0; st >>= 1) {
    if (threadIdx.x < st) {
      red[threadIdx.x] += red[threadIdx.x+st];
      red[256+threadIdx.x] += red[256+threadIdx.x+st];
    }
    __syncthreads();
  }
  if (threadIdx.x == 0) {
    atomicAdd(&stats[tsel*256 + c], red[0]);
    atomicAdd(&stats[tsel*256 + 128 + c], red[256]);
  }
}

// ---------------- BN apply + relu, sum three branches ----------------
__global__ __launch_bounds__(256) void k_bnapply(const float* y1,
    const float* __restrict__ y2, const float* __restrict__ y3,
    const float* __restrict__ stats,
    const float* __restrict__ g1, const float* __restrict__ be1,
    const float* __restrict__ g2, const float* __restrict__ be2,
    const float* __restrict__ g3, const float* __restrict__ be3,
    float* out)
{
  int i4 = blockIdx.x*256 + threadIdx.x;
  int c = (i4 >> 12) & 127;
  const float inv = 1.f/(float)NHW;
  float mu1 = stats[c]*inv;       float v1 = stats[128+c]*inv - mu1*mu1;
  float mu2 = stats[256+c]*inv;   float v2 = stats[384+c]*inv - mu2*mu2;
  float mu3 = stats[512+c]*inv;   float v3 = stats[640+c]*inv - mu3*mu3;
  float s1 = rsqrtf(v1+EPS)*g1[c], s2 = rsqrtf(v2+EPS)*g2[c], s3 = rsqrtf(v3+EPS)*g3[c];
  float o1 = be1[c]-mu1*s1, o2 = be2[c]-mu2*s2, o3_ = be3[c]-mu3*s3;
  float4 a = ((const float4*)y1)[i4];
  float4 bq = ((const float4*)y2)[i4];
  float4 cq = ((const float4*)y3)[i4];
  float4 r;
  r.x = fmaxf(fmaf(a.x,s1,o1),0.f)+fmaxf(fmaf(bq.x,s2,o2),0.f)+fmaxf(fmaf(cq.x,s3,o3_),0.f);
  r.y = fmaxf(fmaf(a.y,s1,o1),0.f)+fmaxf(fmaf(bq.y,s2,o2),0.f)+fmaxf(fmaf(cq.y,s3,o3_),0.f);
  r.z = fmaxf(fmaf(a.z,s1,o1),0.f)+fmaxf(fmaf(bq.z,s2,o2),0.f)+fmaxf(fmaf(cq.z,s3,o3_),0.f);
  r.w = fmaxf(fmaf(a.w,s1,o1),0.f)+fmaxf(fmaf(bq.w,s2,o2),0.f)+fmaxf(fmaf(cq.w,s3,o3_),0.f);
  ((float4*)out)[i4] = r;
}

// ---------------- six depthwise branches summed ----------------
__global__ __launch_bounds__(256) void k_dw(const float* __restrict__ X,
    const float* __restrict__ w1, const float* __restrict__ b1,
    const float* __restrict__ w2, const float* __restrict__ b2,
    const float* __restrict__ w3, const float* __restrict__ b3,
    const float* __restrict__ w4, const float* __restrict__ b4,
    const float* __restrict__ w5, const float* __restrict__ b5,
    const float* __restrict__ w6, const float* __restrict__ b6,
    float* __restrict__ Y)
{
  int lin = blockIdx.x*256 + threadIdx.x;
  int w = lin & 127, h = (lin>>7)&127, c = (lin>>14)&127;
  float hcoef[7], vcoef[7];
  #pragma unroll
  for (int d = 0; d < 7; ++d) { hcoef[d] = w5[c*7+d]; vcoef[d] = w6[c*7+d]; }
  #pragma unroll
  for (int d = 1; d < 6; ++d) { hcoef[d] += w1[c*5+d-1]; vcoef[d] += w2[c*5+d-1]; }
  hcoef[3] += w3[c];
  float acc = b1[c]+b2[c]+b3[c]+b4[c]+b5[c]+b6[c];
  const float* xp = X + ((long)lin >> 14 << 14);
  #pragma unroll
  for (int d = 0; d < 7; ++d) {
    int wq = w + d - 3;
    if ((unsigned)wq < 128u) acc = fmaf(hcoef[d], xp[h*128 + wq], acc);
    int hq = h + d - 3;
    if ((unsigned)hq < 128u) acc = fmaf(vcoef[d], xp[hq*128 + w], acc);
  }
  #pragma unroll
  for (int kh = 0; kh < 3; ++kh) {
    int hq = h + kh - 1;
    if ((unsigned)hq >= 128u) continue;
    #pragma unroll
    for (int kw = 0; kw < 3; ++kw) {
      int wq = w + kw - 1;
      if ((unsigned)wq < 128u) acc = fmaf(w4[c*9+kh*3+kw], xp[hq*128+wq], acc);
    }
  }
  Y[lin] = acc;
}

// ---------------- norms ----------------
__global__ __launch_bounds__(256) void k_normh(const float* __restrict__ out1, float* __restrict__ invn)
{
  __shared__ float red[256];
  int bid = blockIdx.x;
  int h = bid & 127; int bh = bid >> 7;
  int b = bh >> 3, hd = bh & 7;
  const float* p = out1 + ((long)(b*Cc + hd*CH)*Hh + h)*Ww;
  float s = 0.f;
  for (int e = threadIdx.x; e < 2048; e += 256) {
    int c = e >> 7, w = e & 127;
    float v = p[(long)c*HW + w];
    s += v*v;
  }
  red[threadIdx.x] = s; __syncthreads();
  for (int st = 128; st > 0; st >>= 1) {
    if (threadIdx.x < st) red[threadIdx.x] += red[threadIdx.x+st];
    __syncthreads();
  }
  if (threadIdx.x == 0) invn[bid] = 1.f/fmaxf(sqrtf(red[0]), 1e-12f);
}

__global__ __launch_bounds__(256) void k_normw(const float* __restrict__ out1,
    const float* __restrict__ out2, float* __restrict__ invn1w, float* __restrict__ invn2w)
{
  __shared__ float red[256];
  int bid = blockIdx.x;
  int tsel = bid & 1; int bh = bid >> 1; int b = bh >> 3, hd = bh & 7;
  const float* src = tsel ? out2 : out1;
  int t = threadIdx.x;
  int w = t & 127, half = t >> 7;
  const float* p = src + (long)(b*Cc + hd*CH)*HW + w;
  float s = 0.f;
  for (int c = 0; c < CH; ++c)
    for (int h = half; h < 128; h += 2) {
      float v = p[(long)c*HW + h*128];
      s += v*v;
    }
  red[t] = s; __syncthreads();
  if (t < 128) {
    float tot = red[t] + red[t+128];
    float iv = 1.f/fmaxf(sqrtf(tot), 1e-12f);
    (tsel ? invn2w : invn1w)[bh*128 + w] = iv;
  }
}

// ---------------- S = scaled cross-products + softmax -> A1/A2 ----------------
__global__ __launch_bounds__(256,2) void k_attnS(const float* __restrict__ out1,
    const float* __restrict__ out2, const float* __restrict__ invn1h,
    const float* __restrict__ invn1w, const float* __restrict__ invn2w,
    float* __restrict__ A1, float* __restrict__ A2)
{
  __shared__ float As[64*16];
  __shared__ float Bs[16][128];
  __shared__ float Smat[64*132];
  int bid = blockIdx.x;
  int wt = bid & 1, hd = (bid>>1)&7, b = (bid>>4)&7, type = bid>>7;
  int w0 = wt*64;
  int t = threadIdx.x;
  int n = t & 127, wl2 = t >> 7;
  const float* srcA = type ? out1 : out2;
  const float* srcB = type ? out2 : out1;
  long slab = (long)(b*Cc + hd*CH)*HW;
  float acc[32];
  #pragma unroll
  for (int j = 0; j < 32; ++j) acc[j] = 0.f;
  for (int kc = 0; kc < 128; ++kc) {
    int cci = kc >> 3;
    int in0 = (kc & 7) << 4;
    const float* pa = srcA + slab + (long)cci*HW;
    const float* pb = srcB + slab + (long)cci*HW;
    __syncthreads();
    for (int e = t; e < 1024; e += 256) {
      int kl = e >> 6, wl = e & 63;
      As[wl*16 + kl] = pa[(in0+kl)*128 + w0 + wl];
    }
    if (type) {
      for (int e = t; e < 512; e += 256) {
        int kl = e >> 5, q = e & 31;
        *(float4*)&Bs[kl][q*4] = *(const float4*)&pb[(in0+kl)*128 + q*4];
      }
    } else {
      int nn = t >> 1, pq = t & 1;
      float4 v0 = *(const float4*)&pb[nn*128 + in0 + pq*4];
      float4 v1 = *(const float4*)&pb[nn*128 + in0 + 8 + pq*4];
      Bs[pq*4+0][nn] = v0.x; Bs[pq*4+1][nn] = v0.y;
      Bs[pq*4+2][nn] = v0.z; Bs[pq*4+3][nn] = v0.w;
      Bs[8+pq*4+0][nn] = v1.x; Bs[8+pq*4+1][nn] = v1.y;
      Bs[8+pq*4+2][nn] = v1.z; Bs[8+pq*4+3][nn] = v1.w;
    }
    __syncthreads();
    #pragma unroll
    for (int k4 = 0; k4 < 16; k4 += 4) {
      float bv0 = Bs[k4+0][n], bv1 = Bs[k4+1][n], bv2 = Bs[k4+2][n], bv3 = Bs[k4+3][n];
      #pragma unroll
      for (int j = 0; j < 32; ++j) {
        float4 a4 = *(const float4*)&As[(wl2*32+j)*16 + k4];
        acc[j] = fmaf(a4.x, bv0, acc[j]);
        acc[j] = fmaf(a4.y, bv1, acc[j]);
        acc[j] = fmaf(a4.z, bv2, acc[j]);
        acc[j] = fmaf(a4.w, bv3, acc[j]);
      }
    }
  }
  int bh128 = ((b<<3)+hd) << 7;
  const float* invrow = type ? invn1w : invn2w;
  const float* invcol = type ? invn2w : invn1h;
  float scol = invcol[bh128 + n];
  #pragma unroll
  for (int j = 0; j < 32; ++j) {
    int row = wl2*32 + j;
    Smat[row*132 + n] = acc[j] * invrow[bh128 + w0 + row] * scol;
  }
  __syncthreads();
  int row = t >> 2, li = t & 3;
  const float4* rp = (const float4*)&Smat[row*132 + li*32];
  float4 v[8];
  float mx = -1e30f;
  #pragma unroll
  for (int q = 0; q < 8; ++q) {
    v[q] = rp[q];
    mx = fmaxf(mx, fmaxf(fmaxf(v[q].x,v[q].y), fmaxf(v[q].z,v[q].w)));
  }
  mx = fmaxf(mx, __shfl_xor(mx, 1));
  mx = fmaxf(mx, __shfl_xor(mx, 2));
  float sum = 0.f;
  #pragma unroll
  for (int q = 0; q < 8; ++q) {
    v[q].x = __expf(v[q].x - mx); v[q].y = __expf(v[q].y - mx);
    v[q].z = __expf(v[q].z - mx); v[q].w = __expf(v[q].w - mx);
    sum += v[q].x+v[q].y+v[q].z+v[q].w;
  }
  sum += __shfl_xor(sum, 1);
  sum += __shfl_xor(sum, 2);
  float inv = 1.f/sum;
  float* Ao = (type ? A2 : A1) + (long)bh128*128 + (w0+row)*128 + li*32;
  #pragma unroll
  for (int q = 0; q < 8; ++q) {
    float4 r; r.x=v[q].x*inv; r.y=v[q].y*inv; r.z=v[q].z*inv; r.w=v[q].w*inv;
    ((float4*)Ao)[q] = r;
  }
}

// ---------------- o34 = A1 @ out1 (over h') + out1*invn1w ----------------
__global__ __launch_bounds__(256,2) void k_o3(const float* __restrict__ out1,
    const float* __restrict__ A1, const float* __restrict__ invn1w,
    float* __restrict__ o34)
{
  __shared__ float Ac[2048];     // [k16][h128]
  __shared__ float Xs[2048];     // [k16][w128]
  int bid = blockIdx.x;
  int b = bid >> 7, cc = bid & 127, hd = cc >> 4;
  int t = threadIdx.x;
  int h0 = (t & 15) << 3;
  int w0 = (t >> 4) << 3;
  const float* Ag = A1 + (long)((b<<3)+hd)*16384;
  const float* xp = out1 + (long)(b*Cc+cc)*HW;
  float acc[8][8];
  #pragma unroll
  for (int i = 0; i < 8; ++i)
    #pragma unroll
    for (int j = 0; j < 8; ++j) acc[i][j] = 0.f;
  for (int kc = 0; kc < 8; ++kc) {
    __syncthreads();
    { int e = t;
      #pragma unroll
      for (int r = 0; r < 2; ++r, e += 256) {
        int hh = e >> 2, q = e & 3;
        float4 v = *(const float4*)&Ag[hh*128 + kc*16 + q*4];
        Ac[(q*4+0)*128 + hh] = v.x;
        Ac[(q*4+1)*128 + hh] = v.y;
        Ac[(q*4+2)*128 + hh] = v.z;
        Ac[(q*4+3)*128 + hh] = v.w;
      }
    }
    { const float4* xsrc = (const float4*)(xp + kc*2048);
      ((float4*)Xs)[t]       = xsrc[t];
      ((float4*)Xs)[t + 256] = xsrc[t + 256]; }
    __syncthreads();
    #pragma unroll
    for (int k = 0; k < 16; ++k) {
      float4 aa = *(const float4*)&Ac[k*128 + h0];
      float4 ab = *(const float4*)&Ac[k*128 + h0 + 4];
      float4 xa = *(const float4*)&Xs[k*128 + w0];
      float4 xb = *(const float4*)&Xs[k*128 + w0 + 4];
      float av[8] = {aa.x,aa.y,aa.z,aa.w,ab.x,ab.y,ab.z,ab.w};
      float xv[8] = {xa.x,xa.y,xa.z,xa.w,xb.x,xb.y,xb.z,xb.w};
      #pragma unroll
      for (int i = 0; i < 8; ++i)
        #pragma unroll
        for (int j = 0; j < 8; ++j)
          acc[i][j] = fmaf(av[i], xv[j], acc[i][j]);
    }
  }
  int bh128 = ((b<<3)+hd) << 7;
  float4 iva = *(const float4*)&invn1w[bh128 + w0];
  float4 ivb = *(const float4*)&invn1w[bh128 + w0 + 4];
  float iv[8] = {iva.x,iva.y,iva.z,iva.w,ivb.x,ivb.y,ivb.z,ivb.w};
  #pragma unroll
  for (int i = 0; i < 8; ++i) {
    long idx = (long)(b*Cc+cc)*HW + (h0+i)*128 + w0;
    float4 u0 = *(const float4*)&xp[(h0+i)*128 + w0];
    float4 u1 = *(const float4*)&xp[(h0+i)*128 + w0 + 4];
    float4 r0, r1;
    r0.x = acc[i][0] + u0.x*iv[0]; r0.y = acc[i][1] + u0.y*iv[1];
    r0.z = acc[i][2] + u0.z*iv[2]; r0.w = acc[i][3] + u0.w*iv[3];
    r1.x = acc[i][4] + u1.x*iv[4]; r1.y = acc[i][5] + u1.y*iv[5];
    r1.z = acc[i][6] + u1.z*iv[6]; r1.w = acc[i][7] + u1.w*iv[7];
    *(float4*)&o34[idx] = r0;
    *(float4*)&o34[idx+4] = r1;
  }
}

// ---------------- o34 += out2 @ A2^T (over w') ----------------
__global__ __launch_bounds__(256,2) void k_o4(const float* __restrict__ out2,
    const float* __restrict__ A2, float* o34)
{
  __shared__ float Xk[2048];
  __shared__ float An[2048];
  int bid = blockIdx.x;
  int b = bid >> 7, cc = bid & 127, hd = cc >> 4;
  int t = threadIdx.x;
  int h0 = (t & 15) << 3;
  int w0 = (t >> 4) << 3;
  const float* Ag = A2 + (long)((b<<3)+hd)*16384;
  const float* xp = out2 + (long)(b*Cc+cc)*HW;
  float acc[8][8];
  #pragma unroll
  for (int i = 0; i < 8; ++i)
    #pragma unroll
    for (int j = 0; j < 8; ++j) acc[i][j] = 0.f;
  for (int kc = 0; kc < 8; ++kc) {
    __syncthreads();
    { int e = t;
      #pragma unroll
      for (int r = 0; r < 2; ++r, e += 256) {
        int hh = e >> 2, q = e & 3;
        float4 v = *(const float4*)&xp[hh*128 + kc*16 + q*4];
        Xk[(q*4+0)*128 + hh] = v.x;
        Xk[(q*4+1)*128 + hh] = v.y;
        Xk[(q*4+2)*128 + hh] = v.z;
        Xk[(q*4+3)*128 + hh] = v.w;
      }
    }
    { int e = t;
      #pragma unroll
      for (int r = 0; r < 2; ++r, e += 256) {
        int ww = e >> 2, q = e & 3;
        float4 v = *(const float4*)&Ag[ww*128 + kc*16 + q*4];
        An[(q*4+0)*128 + ww] = v.x;
        An[(q*4+1)*128 + ww] = v.y;
        An[(q*4+2)*128 + ww] = v.z;
        An[(q*4+3)*128 + ww] = v.w;
      }
    }
    __syncthreads();
    #pragma unroll
    for (int k = 0; k < 16; ++k) {
      float4 aa = *(const float4*)&Xk[k*128 + h0];
      float4 ab = *(const float4*)&Xk[k*128 + h0 + 4];
      float4 xa = *(const float4*)&An[k*128 + w0];
      float4 xb = *(const float4*)&An[k*128 + w0 + 4];
      float av[8] = {aa.x,aa.y,aa.z,aa.w,ab.x,ab.y,ab.z,ab.w};
      float xv[8] = {xa.x,xa.y,xa.z,xa.w,xb.x,xb.y,xb.z,xb.w};
      #pragma unroll
      for (int i = 0; i < 8; ++i)
        #pragma unroll
        for (int j = 0; j < 8; ++j)
          acc[i][j] = fmaf(av[i], xv[j], acc[i][j]);
    }
  }
  #pragma unroll
  for (int i = 0; i < 8; ++i) {
    long idx = (long)(b*Cc+cc)*HW + (h0+i)*128 + w0;
    float4 r0 = *(const float4*)&o34[idx];
    float4 r1 = *(const float4*)&o34[idx+4];
    r0.x += acc[i][0]; r0.y += acc[i][1]; r0.z += acc[i][2]; r0.w += acc[i][3];
    r1.x += acc[i][4]; r1.y += acc[i][5]; r1.z += acc[i][6]; r1.w += acc[i][7];
    *(float4*)&o34[idx] = r0;
    *(float4*)&o34[idx+4] = r1;
  }
}

// ---------------- o34 += out2^T * invn2w ----------------
__global__ __launch_bounds__(256) void k_tadd(const float* __restrict__ out2,
    const float* __restrict__ invn2w, float* o34)
{
  __shared__ float Ls[32][33];
  int bid = blockIdx.x;
  int wi = bid & 3, hi = (bid>>2)&3, cc = (bid>>4)&127, b = bid>>11;
  int h0 = hi*32, w0 = wi*32;
  int hd = cc >> 4;
  int t = threadIdx.x;
  int li = t & 31, r0 = t >> 5;
  const float* p = out2 + (long)(b*Cc+cc)*HW;
  for (int r = r0; r < 32; r += 8)
    Ls[r][li] = p[(w0+r)*128 + h0 + li];
  __syncthreads();
  float* q = o34 + (long)(b*Cc+cc)*HW;
  for (int r = r0; r < 32; r += 8) {
    float iv = invn2w[(((b<<3)+hd)<<7) + h0 + r];
    q[(h0+r)*128 + w0 + li] += Ls[li][r] * iv;
  }
}

extern "C" void kernel_launch(void* const* d_in, const int* in_sizes, int n_in,
                              void* d_out, int out_size, void* d_ws, size_t ws_size,
                              hipStream_t stream)
{
  const float* x    = (const float*)d_in[0];
  const float* ln_w = (const float*)d_in[1];
  const float* ln_b = (const float*)d_in[2];
  const float* wd1  = (const float*)d_in[3];
  const float* gd1  = (const float*)d_in[4];
  const float* bd1  = (const float*)d_in[5];
  const float* wd2  = (const float*)d_in[6];
  const float* gd2  = (const float*)d_in[7];
  const float* bd2  = (const float*)d_in[8];
  const float* wd3  = (const float*)d_in[9];
  const float* gd3  = (const float*)d_in[10];
  const float* bd3  = (const float*)d_in[11];
  const float* w_out1 = (const float*)d_in[12];
  const float* w1 = (const float*)d_in[13]; const float* b1 = (const float*)d_in[14];
  const float* w2 = (const float*)d_in[15]; const float* b2 = (const float*)d_in[16];
  const float* w3 = (const float*)d_in[17]; const float* b3 = (const float*)d_in[18];
  const float* w4 = (const float*)d_in[19]; const float* b4 = (const float*)d_in[20];
  const float* w5 = (const float*)d_in[21]; const float* b5 = (const float*)d_in[22];
  const float* w6 = (const float*)d_in[23]; const float* b6 = (const float*)d_in[24];
  const float* w_out2 = (const float*)d_in[25];
  float* out = (float*)d_out;

  const long SLAB = 16777216L;
  float* buf0 = (float*)d_ws;            // xb -> x1 -> out1 -> ob
  float* buf1 = buf0 + SLAB;             // y1 -> s -> ab -> o34
  float* buf2 = buf1 + SLAB;             // y2 -> out2
  float* dbuf = out;                     // y3 -> sb -> att -> final output
  float* A1 = buf2 + SLAB;
  float* A2 = A1 + 1048576;
  float* stats = A2 + 1048576;
  float* invn1h = stats + 768;
  float* invn1w = invn1h + 8192;
  float* invn2w = invn1w + 8192;
  short* wb2  = (short*)(invn2w + 8192);
  short* wb3  = wb2 + 147456;
  short* wb1  = wb3 + 147456;
  short* wbo1 = wb1 + 16384;
  short* wbo2 = wbo1 + 16384;
  short* xb = (short*)buf0;   // bf16 NHWC of x   (dead after y3)
  short* sb = (short*)dbuf;   // bf16 NHWC of s   (dead after out2 conv)
  short* ab = (short*)buf1;   // bf16 NHWC of att (dead after out1 conv)
  short* ob = (short*)buf0;   // bf16 NHWC of o34 (dead after final conv)

  k_zero<<<3, 256, 0, stream>>>(stats, 768);
  k_reorg3b<<<576, 256, 0, stream>>>(wd2, wb2);
  k_reorg3b<<<576, 256, 0, stream>>>(wd3, wb3);
  k_cast<<<64, 256, 0, stream>>>(wd1, wb1);
  k_cast<<<64, 256, 0, stream>>>(w_out1, wbo1);
  k_cast<<<64, 256, 0, stream>>>(w_out2, wbo2);

  k_nhwc<<<16384, 256, 0, stream>>>(x, xb);
  k_mconv<<<1024, 256, 0, stream>>>(xb, wb1, nullptr, buf1, 1, 1);   // y1
  k_mconv<<<1024, 256, 0, stream>>>(xb, wb2, nullptr, buf2, 3, 6);   // y2
  k_mconv<<<1024, 256, 0, stream>>>(xb, wb3, nullptr, dbuf, 3, 12);  // y3
  k_bnstats<<<3072, 256, 0, stream>>>(buf1, buf2, dbuf, stats);
  k_bnapply<<<16384, 256, 0, stream>>>(buf1, buf2, dbuf, stats,
                                       gd1, bd1, gd2, bd2, gd3, bd3, buf1); // s
  k_ln<<<512, 256, 0, stream>>>(x, ln_w, ln_b, buf0);                // x1 (xb dead)
  k_nhwc<<<16384, 256, 0, stream>>>(buf1, sb);                       // sb (y3 dead)
  k_mconv<<<1024, 256, 0, stream>>>(sb, wbo1, x, buf2, 1, 1);        // out2 (y2 dead)
  k_dw<<<65536, 256, 0, stream>>>(buf0, w1,b1,w2,b2,w3,b3,w4,b4,w5,b5,w6,b6, dbuf); // att (sb dead)
  k_nhwc<<<16384, 256, 0, stream>>>(dbuf, ab);                       // ab (s dead)
  k_mconv<<<1024, 256, 0, stream>>>(ab, wbo2, nullptr, buf0, 1, 1);  // out1 (x1 dead)
  k_normh<<<8192, 256, 0, stream>>>(buf0, invn1h);
  k_normw<<<128, 256, 0, stream>>>(buf0, buf2, invn1w, invn2w);
  k_attnS<<<256, 256, 0, stream>>>(buf0, buf2, invn1h, invn1w, invn2w, A1, A2);
  k_o3<<<1024, 256, 0, stream>>>(buf0, A1, invn1w, buf1);            // o34 (ab dead)
  k_o4<<<1024, 256, 0, stream>>>(buf2, A2, buf1);
  k_tadd<<<16384, 256, 0, stream>>>(buf2, invn2w, buf1);
  k_nhwc<<<16384, 256, 0, stream>>>(buf1, ob);                       // ob (out1 dead)
  k_mconv<<<1024, 256, 0, stream>>>(ob, wbo2, x, out, 1, 1);         // final + x (att dead)
}

// Round 5
// 1549.104 us; speedup vs baseline: 3.3403x; 1.3419x over previous
//
#include <hip/hip_runtime.h>

#define Bb 8
#define Cc 128
#define Hh 128
#define Ww 128
#define HW 16384
#define CHW (Cc*HW)
#define NHW (Bb*HW)
#define CH 16
#define EPS 1e-5f

typedef __attribute__((ext_vector_type(8))) short bf16x8;
typedef __attribute__((ext_vector_type(4))) float f32x4;

static __device__ __forceinline__ short f2b(float f) {
  unsigned u = __float_as_uint(f);
  unsigned lsb = (u >> 16) & 1;
  return (short)((u + 0x7fffu + lsb) >> 16);
}
static __device__ __forceinline__ float b2f(short s) {
  return __uint_as_float(((unsigned)(unsigned short)s) << 16);
}

// ---------------- LayerNorm over channel dim ----------------
__global__ __launch_bounds__(256) void k_ln(const float* __restrict__ x,
    const float* __restrict__ g, const float* __restrict__ be,
    float* __restrict__ y)
{
  int p = blockIdx.x*256 + threadIdx.x;
  int b = p >> 14, hw = p & 16383;
  const float* xp = x + (long)b*CHW + hw;
  float s = 0.f, q = 0.f;
  for (int c = 0; c < Cc; ++c) { float v = xp[c*HW]; s += v; q += v*v; }
  float mu = s * (1.f/Cc);
  float var = q * (1.f/Cc) - mu*mu;
  float rstd = rsqrtf(var + EPS);
  float* yp = y + (long)b*CHW + hw;
  for (int c = 0; c < Cc; ++c) {
    float v = xp[c*HW];
    yp[c*HW] = (v - mu) * rstd * g[c] + be[c];
  }
}

// ---------------- 3x3 weight: [co][ci][tap] fp32 -> [tap][co][ci] bf16 ----------------
__global__ __launch_bounds__(256) void k_reorg3b(const float* __restrict__ Wt, short* __restrict__ out)
{
  int idx = blockIdx.x*256 + threadIdx.x;
  int tap = idx >> 14, r = idx & 16383;
  out[idx] = f2b(Wt[r*9 + tap]);
}

__global__ __launch_bounds__(256) void k_cast(const float* __restrict__ in, short* __restrict__ out)
{
  int i = blockIdx.x*256 + threadIdx.x;
  out[i] = f2b(in[i]);
}

__global__ __launch_bounds__(256) void k_zero(float* p, int n)
{
  int i = blockIdx.x*256 + threadIdx.x;
  if (i < n) p[i] = 0.f;
}

// ---------------- NCHW fp32 -> NHWC bf16 ----------------
__global__ __launch_bounds__(256) void k_nhwc(const float* __restrict__ in, short* __restrict__ out)
{
  __shared__ float Ls[32][33];
  int bid = blockIdx.x;
  int hwt = bid & 511, c4 = (bid>>9)&3, b = bid>>11;
  int hw0 = hwt << 5, c0 = c4 << 5;
  int t = threadIdx.x;
  int hl = t & 31, cl = t >> 5;
  const float* p = in + (long)b*CHW + hw0;
  for (int r = cl; r < 32; r += 8)
    Ls[r][hl] = p[(long)(c0+r)*HW + hl];
  __syncthreads();
  short* q = out + ((long)b*HW + hw0)*Cc + c0;
  int ccl = t & 31, hl0 = t >> 5;
  for (int r = hl0; r < 32; r += 8)
    q[(long)r*Cc + ccl] = f2b(Ls[ccl][r]);
}

// ---------------- MFMA conv (1x1 or dilated 3x3) ----------------
__global__ __launch_bounds__(256,2) void k_mconv(const short* __restrict__ X,
    const short* __restrict__ W, const float* __restrict__ res,
    float* __restrict__ Y, int k3, int dil)
{
  __shared__ short Ws[128*40];
  __shared__ short Xt[128*40];
  int b = blockIdx.x >> 7, h = blockIdx.x & 127;
  int t = threadIdx.x;
  int wave = t >> 6, lane = t & 63;
  int co0 = (wave >> 1) << 6, sp0 = (wave & 1) << 6;
  int lm = lane & 15, quad = lane >> 4;
  f32x4 acc[4][4];
  #pragma unroll
  for (int i = 0; i < 4; ++i)
    #pragma unroll
    for (int j = 0; j < 4; ++j) acc[i][j] = (f32x4){0.f,0.f,0.f,0.f};
  int half = k3 >> 1;
  int sco = t >> 1, spart = t & 1;
  for (int kh = 0; kh < k3; ++kh) {
    int hs = h + (kh - half)*dil;
    if ((unsigned)hs >= (unsigned)Hh) continue;
    for (int kw = 0; kw < k3; ++kw) {
      int dw = (kw - half)*dil;
      const short* wt = W + (kh*k3 + kw)*16384;
      const short* xr = X + ((long)(b*Hh + hs)*Ww)*Cc;
      int wsrc = sco + dw;
      bool inb = (unsigned)wsrc < (unsigned)Ww;
      for (int kc = 0; kc < 4; ++kc) {
        int k0 = kc << 5;
        __syncthreads();
        { float4 a0 = *(const float4*)(wt + sco*128 + k0 + spart*16);
          float4 a1 = *(const float4*)(wt + sco*128 + k0 + spart*16 + 8);
          *(float4*)(Ws + sco*40 + spart*16) = a0;
          *(float4*)(Ws + sco*40 + spart*16 + 8) = a1; }
        { float4 x0 = {0.f,0.f,0.f,0.f}, x1 = {0.f,0.f,0.f,0.f};
          if (inb) {
            x0 = *(const float4*)(xr + (long)wsrc*Cc + k0 + spart*16);
            x1 = *(const float4*)(xr + (long)wsrc*Cc + k0 + spart*16 + 8);
          }
          *(float4*)(Xt + sco*40 + spart*16) = x0;
          *(float4*)(Xt + sco*40 + spart*16 + 8) = x1; }
        __syncthreads();
        bf16x8 af[4], bfr[4];
        #pragma unroll
        for (int i = 0; i < 4; ++i)
          af[i] = *(const bf16x8*)(Ws + (co0 + i*16 + lm)*40 + quad*8);
        #pragma unroll
        for (int j = 0; j < 4; ++j)
          bfr[j] = *(const bf16x8*)(Xt + (sp0 + j*16 + lm)*40 + quad*8);
        #pragma unroll
        for (int i = 0; i < 4; ++i)
          #pragma unroll
          for (int j = 0; j < 4; ++j)
            acc[i][j] = __builtin_amdgcn_mfma_f32_16x16x32_bf16(af[i], bfr[j], acc[i][j], 0, 0, 0);
      }
    }
  }
  #pragma unroll
  for (int i = 0; i < 4; ++i) {
    int co = co0 + i*16 + quad*4;
    #pragma unroll
    for (int j = 0; j < 4; ++j) {
      int wc = sp0 + j*16 + lm;
      long base = ((long)(b*Cc + co)*Hh + h)*Ww + wc;
      #pragma unroll
      for (int r = 0; r < 4; ++r) {
        float v = acc[i][j][r];
        long idx = base + (long)r*HW;
        if (res) v += res[idx];
        Y[idx] = v;
      }
    }
  }
}

// ---------------- BN batch stats ----------------
__global__ __launch_bounds__(256) void k_bnstats(const float* __restrict__ y1,
    const float* __restrict__ y2, const float* __restrict__ y3,
    float* __restrict__ stats)
{
  __shared__ float red[512];
  int bid = blockIdx.x;
  int tsel = bid >> 10;
  int rem = bid & 1023;
  int c = rem >> 3, b = rem & 7;
  const float* y = tsel == 0 ? y1 : (tsel == 1 ? y2 : y3);
  const float* p = y + (long)(b*Cc + c)*HW;
  float s = 0.f, q = 0.f;
  for (int i = threadIdx.x; i < HW; i += 256) { float v = p[i]; s += v; q += v*v; }
  red[threadIdx.x] = s; red[256+threadIdx.x] = q;
  __syncthreads();
  for (int st = 128; st > 0; st >>= 1) {
    if (threadIdx.x < st) {
      red[threadIdx.x] += red[threadIdx.x+st];
      red[256+threadIdx.x] += red[256+threadIdx.x+st];
    }
    __syncthreads();
  }
  if (threadIdx.x == 0) {
    atomicAdd(&stats[tsel*256 + c], red[0]);
    atomicAdd(&stats[tsel*256 + 128 + c], red[256]);
  }
}

// ---------------- BN apply + relu, sum three branches ----------------
__global__ __launch_bounds__(256) void k_bnapply(const float* y1,
    const float* __restrict__ y2, const float* __restrict__ y3,
    const float* __restrict__ stats,
    const float* __restrict__ g1, const float* __restrict__ be1,
    const float* __restrict__ g2, const float* __restrict__ be2,
    const float* __restrict__ g3, const float* __restrict__ be3,
    float* out)
{
  int i4 = blockIdx.x*256 + threadIdx.x;
  int c = (i4 >> 12) & 127;
  const float inv = 1.f/(float)NHW;
  float mu1 = stats[c]*inv;       float v1 = stats[128+c]*inv - mu1*mu1;
  float mu2 = stats[256+c]*inv;   float v2 = stats[384+c]*inv - mu2*mu2;
  float mu3 = stats[512+c]*inv;   float v3 = stats[640+c]*inv - mu3*mu3;
  float s1 = rsqrtf(v1+EPS)*g1[c], s2 = rsqrtf(v2+EPS)*g2[c], s3 = rsqrtf(v3+EPS)*g3[c];
  float o1 = be1[c]-mu1*s1, o2 = be2[c]-mu2*s2, o3_ = be3[c]-mu3*s3;
  float4 a = ((const float4*)y1)[i4];
  float4 bq = ((const float4*)y2)[i4];
  float4 cq = ((const float4*)y3)[i4];
  float4 r;
  r.x = fmaxf(fmaf(a.x,s1,o1),0.f)+fmaxf(fmaf(bq.x,s2,o2),0.f)+fmaxf(fmaf(cq.x,s3,o3_),0.f);
  r.y = fmaxf(fmaf(a.y,s1,o1),0.f)+fmaxf(fmaf(bq.y,s2,o2),0.f)+fmaxf(fmaf(cq.y,s3,o3_),0.f);
  r.z = fmaxf(fmaf(a.z,s1,o1),0.f)+fmaxf(fmaf(bq.z,s2,o2),0.f)+fmaxf(fmaf(cq.z,s3,o3_),0.f);
  r.w = fmaxf(fmaf(a.w,s1,o1),0.f)+fmaxf(fmaf(bq.w,s2,o2),0.f)+fmaxf(fmaf(cq.w,s3,o3_),0.f);
  ((float4*)out)[i4] = r;
}

// ---------------- six depthwise branches summed ----------------
__global__ __launch_bounds__(256) void k_dw(const float* __restrict__ X,
    const float* __restrict__ w1, const float* __restrict__ b1,
    const float* __restrict__ w2, const float* __restrict__ b2,
    const float* __restrict__ w3, const float* __restrict__ b3,
    const float* __restrict__ w4, const float* __restrict__ b4,
    const float* __restrict__ w5, const float* __restrict__ b5,
    const float* __restrict__ w6, const float* __restrict__ b6,
    float* __restrict__ Y)
{
  int lin = blockIdx.x*256 + threadIdx.x;
  int w = lin & 127, h = (lin>>7)&127, c = (lin>>14)&127;
  float hcoef[7], vcoef[7];
  #pragma unroll
  for (int d = 0; d < 7; ++d) { hcoef[d] = w5[c*7+d]; vcoef[d] = w6[c*7+d]; }
  #pragma unroll
  for (int d = 1; d < 6; ++d) { hcoef[d] += w1[c*5+d-1]; vcoef[d] += w2[c*5+d-1]; }
  hcoef[3] += w3[c];
  float acc = b1[c]+b2[c]+b3[c]+b4[c]+b5[c]+b6[c];
  const float* xp = X + ((long)lin >> 14 << 14);
  #pragma unroll
  for (int d = 0; d < 7; ++d) {
    int wq = w + d - 3;
    if ((unsigned)wq < 128u) acc = fmaf(hcoef[d], xp[h*128 + wq], acc);
    int hq = h + d - 3;
    if ((unsigned)hq < 128u) acc = fmaf(vcoef[d], xp[hq*128 + w], acc);
  }
  #pragma unroll
  for (int kh = 0; kh < 3; ++kh) {
    int hq = h + kh - 1;
    if ((unsigned)hq >= 128u) continue;
    #pragma unroll
    for (int kw = 0; kw < 3; ++kw) {
      int wq = w + kw - 1;
      if ((unsigned)wq < 128u) acc = fmaf(w4[c*9+kh*3+kw], xp[hq*128+wq], acc);
    }
  }
  Y[lin] = acc;
}

// ---------------- norms ----------------
__global__ __launch_bounds__(256) void k_normh(const float* __restrict__ out1, float* __restrict__ invn)
{
  __shared__ float red[256];
  int bid = blockIdx.x;
  int h = bid & 127; int bh = bid >> 7;
  int b = bh >> 3, hd = bh & 7;
  const float* p = out1 + ((long)(b*Cc + hd*CH)*Hh + h)*Ww;
  float s = 0.f;
  for (int e = threadIdx.x; e < 2048; e += 256) {
    int c = e >> 7, w = e & 127;
    float v = p[(long)c*HW + w];
    s += v*v;
  }
  red[threadIdx.x] = s; __syncthreads();
  for (int st = 128; st > 0; st >>= 1) {
    if (threadIdx.x < st) red[threadIdx.x] += red[threadIdx.x+st];
    __syncthreads();
  }
  if (threadIdx.x == 0) invn[bid] = 1.f/fmaxf(sqrtf(red[0]), 1e-12f);
}

__global__ __launch_bounds__(256) void k_normw(const float* __restrict__ out1,
    const float* __restrict__ out2, float* __restrict__ invn1w, float* __restrict__ invn2w)
{
  __shared__ float red[256];
  int bid = blockIdx.x;
  int tsel = bid & 1; int bh = bid >> 1; int b = bh >> 3, hd = bh & 7;
  const float* src = tsel ? out2 : out1;
  int t = threadIdx.x;
  int w = t & 127, half = t >> 7;
  const float* p = src + (long)(b*Cc + hd*CH)*HW + w;
  float s = 0.f;
  for (int c = 0; c < CH; ++c)
    for (int h = half; h < 128; h += 2) {
      float v = p[(long)c*HW + h*128];
      s += v*v;
    }
  red[t] = s; __syncthreads();
  if (t < 128) {
    float tot = red[t] + red[t+128];
    float iv = 1.f/fmaxf(sqrtf(tot), 1e-12f);
    (tsel ? invn2w : invn1w)[bh*128 + w] = iv;
  }
}

// ---------------- transpose-cast: out?T[b][hd][w][c*128+h] = out?[b][hd*16+c][h][w] ----------------
__global__ __launch_bounds__(256) void k_t12(const float* __restrict__ out1,
    const float* __restrict__ out2, short* __restrict__ out1T, short* __restrict__ out2T)
{
  __shared__ float Ls[32][33];
  int bid = blockIdx.x;
  int wt = bid&3, ht=(bid>>2)&3, c=(bid>>4)&127, b=(bid>>11)&7, src=bid>>14;
  const float* in = (src ? out2 : out1) + (long)(b*128+c)*16384;
  short* outp = (src ? out2T : out1T) + ((long)(b*8 + (c>>4))*128)*2048 + (c&15)*128;
  int h0 = ht*32, w0 = wt*32;
  int t = threadIdx.x, li = t&31, r0 = t>>5;
  for (int r = r0; r < 32; r += 8)
    Ls[r][li] = in[(h0+r)*128 + w0 + li];
  __syncthreads();
  for (int r = r0; r < 32; r += 8)
    outp[(long)(w0+r)*2048 + h0 + li] = f2b(Ls[li][r]);
}

// ---------------- casts: out1H[b][hd][h][c*128+p] (regroup) + out2H (plain NCHW) ----------------
__global__ __launch_bounds__(256) void k_h12(const float* __restrict__ out1,
    const float* __restrict__ out2, short* __restrict__ out1H, short* __restrict__ out2H)
{
  int bid = blockIdx.x;
  int src = bid >> 13;
  long e = ((long)(bid & 8191)*256 + threadIdx.x) * 8;
  const float* p;
  short* dst;
  if (src) { p = out2 + e; dst = out2H + e; }
  else {
    int c = (int)((e>>7)&15), h = (int)((e>>11)&127), hd=(int)((e>>18)&7), b=(int)(e>>21);
    int pp = (int)(e & 127);
    p = out1 + (((long)(b*128 + hd*16 + c)*128 + h)*128 + pp);
    dst = out1H + e;
  }
  int4 o;
  o.x = ((int)(unsigned short)f2b(p[1])<<16) | (unsigned short)f2b(p[0]);
  o.y = ((int)(unsigned short)f2b(p[3])<<16) | (unsigned short)f2b(p[2]);
  o.z = ((int)(unsigned short)f2b(p[5])<<16) | (unsigned short)f2b(p[4]);
  o.w = ((int)(unsigned short)f2b(p[7])<<16) | (unsigned short)f2b(p[6]);
  *(int4*)dst = o;
}

// ---------------- MFMA attention S + softmax -> A1/A2 (bf16 row-major) ----------------
// grid 128 = type(2) x bh(64). Block: 128 rows x 128 cols, K=2048.
// 4 waves x (32 rows x 128 cols) so each softmax row lives in one wave.
__global__ __launch_bounds__(256) void k_attnS_m(
    const short* __restrict__ out1T, const short* __restrict__ out2T,
    const short* __restrict__ out1H,
    const float* __restrict__ invn1h, const float* __restrict__ invn1w,
    const float* __restrict__ invn2w,
    short* __restrict__ A1b, short* __restrict__ A2b)
{
  __shared__ short As[128*72];
  __shared__ short Bs[128*72];
  int bid = blockIdx.x;
  int type = bid >> 6, bh = bid & 63;
  const short* Aop = (type ? out1T : out2T) + (long)bh*262144;
  const short* Bop = (type ? out2T : out1H) + (long)bh*262144;
  const float* invrow = (type ? invn1w : invn2w) + bh*128;
  const float* invcol = (type ? invn2w : invn1h) + bh*128;
  short* Aout = (type ? A2b : A1b) + (long)bh*16384;
  int t = threadIdx.x;
  int wave = t >> 6, lane = t & 63, lm = lane & 15, quad = lane >> 4;
  int m0 = wave << 5;
  f32x4 acc[2][8];
  #pragma unroll
  for (int i = 0; i < 2; ++i)
    #pragma unroll
    for (int j = 0; j < 8; ++j) acc[i][j] = (f32x4){0.f,0.f,0.f,0.f};
  for (int kc = 0; kc < 32; ++kc) {
    int k0 = kc << 6;
    __syncthreads();
    #pragma unroll
    for (int i = 0; i < 4; ++i) {
      int e = t + i*256;
      int row = e >> 3, off = (e & 7) << 3;
      *(float4*)(As + row*72 + off) = *(const float4*)(Aop + (long)row*2048 + k0 + off);
      *(float4*)(Bs + row*72 + off) = *(const float4*)(Bop + (long)row*2048 + k0 + off);
    }
    __syncthreads();
    #pragma unroll
    for (int ks = 0; ks < 64; ks += 32) {
      bf16x8 af[2], bfj[8];
      #pragma unroll
      for (int i = 0; i < 2; ++i)
        af[i] = *(const bf16x8*)(As + (m0 + i*16 + lm)*72 + ks + quad*8);
      #pragma unroll
      for (int j = 0; j < 8; ++j)
        bfj[j] = *(const bf16x8*)(Bs + (j*16 + lm)*72 + ks + quad*8);
      #pragma unroll
      for (int i = 0; i < 2; ++i)
        #pragma unroll
        for (int j = 0; j < 8; ++j)
          acc[i][j] = __builtin_amdgcn_mfma_f32_16x16x32_bf16(af[i], bfj[j], acc[i][j], 0, 0, 0);
    }
  }
  float colv[8];
  #pragma unroll
  for (int j = 0; j < 8; ++j) colv[j] = invcol[j*16 + lm];
  #pragma unroll
  for (int i = 0; i < 2; ++i) {
    #pragma unroll
    for (int r = 0; r < 4; ++r) {
      int row = m0 + i*16 + quad*4 + r;
      float rs = invrow[row];
      float sv[8];
      float mx = -1e30f;
      #pragma unroll
      for (int j = 0; j < 8; ++j) {
        sv[j] = acc[i][j][r] * rs * colv[j];
        mx = fmaxf(mx, sv[j]);
      }
      mx = fmaxf(mx, __shfl_xor(mx, 1));
      mx = fmaxf(mx, __shfl_xor(mx, 2));
      mx = fmaxf(mx, __shfl_xor(mx, 4));
      mx = fmaxf(mx, __shfl_xor(mx, 8));
      float sum = 0.f;
      #pragma unroll
      for (int j = 0; j < 8; ++j) { sv[j] = __expf(sv[j] - mx); sum += sv[j]; }
      sum += __shfl_xor(sum, 1);
      sum += __shfl_xor(sum, 2);
      sum += __shfl_xor(sum, 4);
      sum += __shfl_xor(sum, 8);
      float inv = 1.f/sum;
      #pragma unroll
      for (int j = 0; j < 8; ++j)
        Aout[row*128 + j*16 + lm] = f2b(sv[j]*inv);
    }
  }
}

// ---------------- MFMA 128x128x128 GEMM for o3/o4 ----------------
// mode 0: D[h][w] = sum_k A1[h][k]*out1T(c-slice)[w][k]; write = D + out1H*invn1w (q2)
// mode 1: D[h][w] = sum_k out2H(c)[h][k]*A2[w][k];       accumulate +=
__global__ __launch_bounds__(256) void k_o34m(
    const short* __restrict__ A1b, const short* __restrict__ out1T,
    const short* __restrict__ out1H, const float* __restrict__ invn1w,
    const short* __restrict__ out2H, const short* __restrict__ A2b,
    float* __restrict__ o34, int mode)
{
  __shared__ short As[128*72];
  __shared__ short Bs[128*72];
  int bid = blockIdx.x;
  const short *Abase, *Bbase;
  long Astride, Bstride;
  float* O;
  const short* R = nullptr;
  const float* inw = nullptr;
  if (mode == 0) {
    int c = bid & 15, hd = (bid>>4)&7, b = bid>>7;
    int bh = b*8+hd;
    Abase = A1b + (long)bh*16384; Astride = 128;
    Bbase = out1T + (long)bh*262144 + c*128; Bstride = 2048;
    O = o34 + (long)(b*128 + hd*16 + c)*16384;
    R = out1H + (long)bh*262144 + c*128;
    inw = invn1w + bh*128;
  } else {
    int cf = bid & 127, b = bid >> 7;
    int bh = b*8 + (cf>>4);
    Abase = out2H + (long)(b*128+cf)*16384; Astride = 128;
    Bbase = A2b + (long)bh*16384; Bstride = 128;
    O = o34 + (long)(b*128+cf)*16384;
  }
  int t = threadIdx.x;
  int wave = t >> 6, lane = t & 63, lm = lane & 15, quad = lane >> 4;
  int m0 = (wave >> 1) << 6, n0 = (wave & 1) << 6;
  f32x4 acc[4][4];
  #pragma unroll
  for (int i = 0; i < 4; ++i)
    #pragma unroll
    for (int j = 0; j < 4; ++j) acc[i][j] = (f32x4){0.f,0.f,0.f,0.f};
  for (int kc = 0; kc < 2; ++kc) {
    int k0 = kc << 6;
    __syncthreads();
    #pragma unroll
    for (int i = 0; i < 4; ++i) {
      int e = t + i*256;
      int row = e >> 3, off = (e & 7) << 3;
      *(float4*)(As + row*72 + off) = *(const float4*)(Abase + (long)row*Astride + k0 + off);
      *(float4*)(Bs + row*72 + off) = *(const float4*)(Bbase + (long)row*Bstride + k0 + off);
    }
    __syncthreads();
    #pragma unroll
    for (int ks = 0; ks < 64; ks += 32) {
      bf16x8 af[4], bfj[4];
      #pragma unroll
      for (int i = 0; i < 4; ++i)
        af[i] = *(const bf16x8*)(As + (m0 + i*16 + lm)*72 + ks + quad*8);
      #pragma unroll
      for (int j = 0; j < 4; ++j)
        bfj[j] = *(const bf16x8*)(Bs + (n0 + j*16 + lm)*72 + ks + quad*8);
      #pragma unroll
      for (int i = 0; i < 4; ++i)
        #pragma unroll
        for (int j = 0; j < 4; ++j)
          acc[i][j] = __builtin_amdgcn_mfma_f32_16x16x32_bf16(af[i], bfj[j], acc[i][j], 0, 0, 0);
    }
  }
  if (mode == 0) {
    float inwv[4];
    #pragma unroll
    for (int j = 0; j < 4; ++j) inwv[j] = inw[n0 + j*16 + lm];
    #pragma unroll
    for (int i = 0; i < 4; ++i) {
      #pragma unroll
      for (int r = 0; r < 4; ++r) {
        int row = m0 + i*16 + quad*4 + r;
        #pragma unroll
        for (int j = 0; j < 4; ++j) {
          int col = n0 + j*16 + lm;
          float rv = b2f(R[(long)row*2048 + col]);
          O[row*128 + col] = acc[i][j][r] + rv * inwv[j];
        }
      }
    }
  } else {
    #pragma unroll
    for (int i = 0; i < 4; ++i) {
      #pragma unroll
      for (int r = 0; r < 4; ++r) {
        int row = m0 + i*16 + quad*4 + r;
        #pragma unroll
        for (int j = 0; j < 4; ++j) {
          int col = n0 + j*16 + lm;
          O[row*128 + col] += acc[i][j][r];
        }
      }
    }
  }
}

// ---------------- o34 += out2^T * invn2w (q1 term) ----------------
__global__ __launch_bounds__(256) void k_tadd(const float* __restrict__ out2,
    const float* __restrict__ invn2w, float* o34)
{
  __shared__ float Ls[32][33];
  int bid = blockIdx.x;
  int wi = bid & 3, hi = (bid>>2)&3, cc = (bid>>4)&127, b = bid>>11;
  int h0 = hi*32, w0 = wi*32;
  int hd = cc >> 4;
  int t = threadIdx.x;
  int li = t & 31, r0 = t >> 5;
  const float* p = out2 + (long)(b*Cc+cc)*HW;
  for (int r = r0; r < 32; r += 8)
    Ls[r][li] = p[(w0+r)*128 + h0 + li];
  __syncthreads();
  float* q = o34 + (long)(b*Cc+cc)*HW;
  for (int r = r0; r < 32; r += 8) {
    float iv = invn2w[(((b<<3)+hd)<<7) + h0 + r];
    q[(h0+r)*128 + w0 + li] += Ls[li][r] * iv;
  }
}

extern "C" void kernel_launch(void* const* d_in, const int* in_sizes, int n_in,
                              void* d_out, int out_size, void* d_ws, size_t ws_size,
                              hipStream_t stream)
{
  const float* x    = (const float*)d_in[0];
  const float* ln_w = (const float*)d_in[1];
  const float* ln_b = (const float*)d_in[2];
  const float* wd1  = (const float*)d_in[3];
  const float* gd1  = (const float*)d_in[4];
  const float* bd1  = (const float*)d_in[5];
  const float* wd2  = (const float*)d_in[6];
  const float* gd2  = (const float*)d_in[7];
  const float* bd2  = (const float*)d_in[8];
  const float* wd3  = (const float*)d_in[9];
  const float* gd3  = (const float*)d_in[10];
  const float* bd3  = (const float*)d_in[11];
  const float* w_out1 = (const float*)d_in[12];
  const float* w1 = (const float*)d_in[13]; const float* b1 = (const float*)d_in[14];
  const float* w2 = (const float*)d_in[15]; const float* b2 = (const float*)d_in[16];
  const float* w3 = (const float*)d_in[17]; const float* b3 = (const float*)d_in[18];
  const float* w4 = (const float*)d_in[19]; const float* b4 = (const float*)d_in[20];
  const float* w5 = (const float*)d_in[21]; const float* b5 = (const float*)d_in[22];
  const float* w6 = (const float*)d_in[23]; const float* b6 = (const float*)d_in[24];
  const float* w_out2 = (const float*)d_in[25];
  float* out = (float*)d_out;

  const long SLAB = 16777216L;
  float* buf0 = (float*)d_ws;            // xb -> x1 -> out1 -> o34
  float* buf1 = buf0 + SLAB;             // y1 -> s -> ab -> out1H|out2H -> ob
  float* buf2 = buf1 + SLAB;             // y2 -> out2
  float* dbuf = out;                     // y3 -> sb -> att -> out1T|out2T -> final
  float* stats = buf2 + SLAB;
  float* invn1h = stats + 768;
  float* invn1w = invn1h + 8192;
  float* invn2w = invn1w + 8192;
  short* wb2  = (short*)(invn2w + 8192);
  short* wb3  = wb2 + 147456;
  short* wb1  = wb3 + 147456;
  short* wbo1 = wb1 + 16384;
  short* wbo2 = wbo1 + 16384;
  short* A1b  = wbo2 + 16384;
  short* A2b  = A1b + 1048576;

  short* xb = (short*)buf0;
  short* sb = (short*)dbuf;
  short* ab = (short*)buf1;
  short* out1T = (short*)dbuf;
  short* out2T = out1T + 16777216;
  short* out1H = (short*)buf1;
  short* out2H = out1H + 16777216;
  short* ob = (short*)buf1;              // overwrites out1H (dead by then)

  k_zero<<<3, 256, 0, stream>>>(stats, 768);
  k_reorg3b<<<576, 256, 0, stream>>>(wd2, wb2);
  k_reorg3b<<<576, 256, 0, stream>>>(wd3, wb3);
  k_cast<<<64, 256, 0, stream>>>(wd1, wb1);
  k_cast<<<64, 256, 0, stream>>>(w_out1, wbo1);
  k_cast<<<64, 256, 0, stream>>>(w_out2, wbo2);

  k_nhwc<<<16384, 256, 0, stream>>>(x, xb);
  k_mconv<<<1024, 256, 0, stream>>>(xb, wb1, nullptr, buf1, 1, 1);   // y1
  k_mconv<<<1024, 256, 0, stream>>>(xb, wb2, nullptr, buf2, 3, 6);   // y2
  k_mconv<<<1024, 256, 0, stream>>>(xb, wb3, nullptr, dbuf, 3, 12);  // y3
  k_bnstats<<<3072, 256, 0, stream>>>(buf1, buf2, dbuf, stats);
  k_bnapply<<<16384, 256, 0, stream>>>(buf1, buf2, dbuf, stats,
                                       gd1, bd1, gd2, bd2, gd3, bd3, buf1); // s
  k_ln<<<512, 256, 0, stream>>>(x, ln_w, ln_b, buf0);                // x1 (xb dead)
  k_nhwc<<<16384, 256, 0, stream>>>(buf1, sb);                       // sb (y3 dead)
  k_mconv<<<1024, 256, 0, stream>>>(sb, wbo1, x, buf2, 1, 1);        // out2 (y2 dead)
  k_dw<<<65536, 256, 0, stream>>>(buf0, w1,b1,w2,b2,w3,b3,w4,b4,w5,b5,w6,b6, dbuf); // att (sb dead)
  k_nhwc<<<16384, 256, 0, stream>>>(dbuf, ab);                       // ab (s dead)
  k_mconv<<<1024, 256, 0, stream>>>(ab, wbo2, nullptr, buf0, 1, 1);  // out1 (x1 dead)
  k_normh<<<8192, 256, 0, stream>>>(buf0, invn1h);
  k_normw<<<128, 256, 0, stream>>>(buf0, buf2, invn1w, invn2w);
  k_t12<<<32768, 256, 0, stream>>>(buf0, buf2, out1T, out2T);        // (att dead)
  k_h12<<<16384, 256, 0, stream>>>(buf0, buf2, out1H, out2H);        // (ab dead)
  k_attnS_m<<<128, 256, 0, stream>>>(out1T, out2T, out1H,
                                     invn1h, invn1w, invn2w, A1b, A2b);
  k_o34m<<<1024, 256, 0, stream>>>(A1b, out1T, out1H, invn1w,
                                   out2H, A2b, buf0, 0);             // o34 = o3 + q2 (out1 fp32 dead)
  k_o34m<<<1024, 256, 0, stream>>>(A1b, out1T, out1H, invn1w,
                                   out2H, A2b, buf0, 1);             // o34 += o4
  k_tadd<<<16384, 256, 0, stream>>>(buf2, invn2w, buf0);             // o34 += q1
  k_nhwc<<<16384, 256, 0, stream>>>(buf0, ob);                       // ob (out1H dead)
  k_mconv<<<1024, 256, 0, stream>>>(ob, wbo2, x, out, 1, 1);         // final + x (T dead)
}